// Round 1
// baseline (3637.284 us; speedup 1.0000x reference)
//
#include <hip/hip_runtime.h>

#define NN 50000
#define EE 600000
#define HH 128
#define TAU_INV 2.0f   // 1/TAU, TAU=0.5

// ---------- helpers ----------
__device__ __forceinline__ float wsum64(float v) {
#pragma unroll
  for (int m = 32; m >= 1; m >>= 1) v += __shfl_xor(v, m, 64);
  return v;
}

// ---------- CSR build ----------
__global__ void count_k(const int* __restrict__ ei, const int* __restrict__ ea,
                        const int* __restrict__ qp, int* __restrict__ cnt,
                        float* __restrict__ cntq) {
  int e = blockIdx.x * 256 + threadIdx.x;
  if (e >= EE) return;
  int q = *qp;
  int dst = ei[EE + e];
  atomicAdd(&cnt[dst], 1);
  int node = ea[e], he = ea[EE + e];
  atomicAdd(&cnt[NN + he], 1);
  atomicAdd(&cnt[2 * NN + node], 1);
  if (node == q) atomicAdd(&cntq[he], 1.0f);
}

__global__ void derive_k(const int* __restrict__ cnt, float* __restrict__ dinv,
                         float* __restrict__ Binv, float* __restrict__ Dninv) {
  int i = blockIdx.x * 256 + threadIdx.x;
  if (i >= NN) return;
  dinv[i] = rsqrtf((float)(cnt[i] + 1));          // deg includes self-loop
  int b = cnt[NN + i];
  Binv[i] = (b > 0) ? 1.0f / (float)b : 0.0f;
  int d = cnt[2 * NN + i];
  Dninv[i] = (d > 0) ? 1.0f / (float)d : 0.0f;
}

__global__ void scan1(const int* __restrict__ cnt, int* __restrict__ offs,
                      int* __restrict__ aux, int M) {
  __shared__ int s[256];
  int tid = threadIdx.x, gid = blockIdx.x * 256 + tid;
  int v = (gid < M) ? cnt[gid] : 0;
  s[tid] = v;
  __syncthreads();
  for (int d = 1; d < 256; d <<= 1) {
    int t = (tid >= d) ? s[tid - d] : 0;
    __syncthreads();
    s[tid] += t;
    __syncthreads();
  }
  if (gid < M) offs[gid] = s[tid] - v;  // exclusive
  if (tid == 255) aux[blockIdx.x] = s[255];
}

__global__ void scan2(int* __restrict__ aux, int nb) {
  __shared__ int s[1024];
  int tid = threadIdx.x;
  int v = (tid < nb) ? aux[tid] : 0;
  s[tid] = v;
  __syncthreads();
  for (int d = 1; d < 1024; d <<= 1) {
    int t = (tid >= d) ? s[tid - d] : 0;
    __syncthreads();
    s[tid] += t;
    __syncthreads();
  }
  if (tid < nb) aux[tid] = s[tid] - v;  // exclusive over block sums
}

__global__ void scan3(int* __restrict__ offs, const int* __restrict__ aux, int M) {
  int gid = blockIdx.x * 256 + threadIdx.x;
  if (gid < M) offs[gid] += aux[blockIdx.x];
}

__global__ void fill_k(const int* __restrict__ ei, const int* __restrict__ ea,
                       const int* __restrict__ offs, int* __restrict__ cursor,
                       int* __restrict__ slots) {
  int e = blockIdx.x * 256 + threadIdx.x;
  if (e >= EE) return;
  int src = ei[e], dst = ei[EE + e];
  int p = offs[dst] + atomicAdd(&cursor[dst], 1);
  slots[p] = src;
  int node = ea[e], he = ea[EE + e];
  int p2 = offs[NN + he] + atomicAdd(&cursor[NN + he], 1);
  slots[p2] = node;
  int p3 = offs[2 * NN + node] + atomicAdd(&cursor[2 * NN + node], 1);
  slots[p3] = he;
}

// ---------- analytic query-column coefficients ----------
__global__ void shq_k(const int* __restrict__ ei, const int* __restrict__ ea,
                      const int* __restrict__ qp, const float* __restrict__ dinv,
                      const float* __restrict__ Binv, const float* __restrict__ cntq,
                      float* __restrict__ s_hq, float* __restrict__ s_hgq) {
  int e = blockIdx.x * 256 + threadIdx.x;
  if (e >= EE) return;
  int q = *qp;
  int src = ei[e], dst = ei[EE + e];
  if (src == q) atomicAdd(&s_hq[dst], dinv[q] * dinv[dst]);
  int node = ea[e], he = ea[EE + e];
  float t = Binv[he] * cntq[he];
  if (t != 0.0f) atomicAdd(&s_hgq[node], t);
}

__global__ void mask_k(const int* __restrict__ pos, const int* __restrict__ qp,
                       int* __restrict__ maskI, float* __restrict__ s_hq,
                       const float* __restrict__ dinv) {
  int t = threadIdx.x;
  if (t < 100) maskI[pos[t]] = 1;
  __syncthreads();
  if (t == 0) {
    int q = *qp;
    maskI[q] = 0;
    s_hq[q] += dinv[q] * dinv[q];  // self-loop contribution of the query gcn
  }
}

// ---------- GEMM: C[N,128] = op(A[N,128] @ W[128,128] (+bias)) ----------
template <bool BIAS, bool RELU>
__global__ __launch_bounds__(256) void gemm128(const float* __restrict__ A,
                                               const float* __restrict__ W,
                                               const float* __restrict__ bias,
                                               float* __restrict__ C, int nrows) {
  __shared__ float As[64 * 128];
  const int tid = threadIdx.x;
  const int r0 = blockIdx.x * 64;
  {
    const float4* A4 = (const float4*)A;
    float4* As4 = (float4*)As;
#pragma unroll
    for (int t = 0; t < 8; ++t) {
      int v = t * 256 + tid;
      int row = v >> 5, c4 = v & 31;
      int gr = r0 + row;
      float4 val = make_float4(0.f, 0.f, 0.f, 0.f);
      if (gr < nrows) val = A4[(size_t)gr * 32 + c4];
      As4[v] = val;
    }
  }
  __syncthreads();
  const int tx = tid & 15, ty = tid >> 4;
  const int cb = tx * 8, rb = ty * 4;
  float acc[4][8];
#pragma unroll
  for (int i = 0; i < 4; ++i)
#pragma unroll
    for (int j = 0; j < 8; ++j) acc[i][j] = 0.f;
  const float4* W4 = (const float4*)W;
  for (int k = 0; k < 128; k += 4) {
    float a[4][4];
#pragma unroll
    for (int i = 0; i < 4; ++i) {
      float4 t4 = *(const float4*)&As[(rb + i) * 128 + k];
      a[i][0] = t4.x; a[i][1] = t4.y; a[i][2] = t4.z; a[i][3] = t4.w;
    }
#pragma unroll
    for (int kk = 0; kk < 4; ++kk) {
      float4 w0 = W4[(k + kk) * 32 + (cb >> 2)];
      float4 w1 = W4[(k + kk) * 32 + (cb >> 2) + 1];
      float wv[8] = {w0.x, w0.y, w0.z, w0.w, w1.x, w1.y, w1.z, w1.w};
#pragma unroll
      for (int i = 0; i < 4; ++i)
#pragma unroll
        for (int j = 0; j < 8; ++j) acc[i][j] = fmaf(a[i][kk], wv[j], acc[i][j]);
    }
  }
#pragma unroll
  for (int i = 0; i < 4; ++i) {
    int gr = r0 + rb + i;
    if (gr >= nrows) continue;
#pragma unroll
    for (int j = 0; j < 8; j += 4) {
      float o[4];
#pragma unroll
      for (int jj = 0; jj < 4; ++jj) {
        float v = acc[i][j + jj];
        if (BIAS) v += bias[cb + j + jj];
        if (RELU) v = fmaxf(v, 0.f);
        o[jj] = v;
      }
      *(float4*)&C[(size_t)gr * 128 + cb + j] = make_float4(o[0], o[1], o[2], o[3]);
    }
  }
}

// ---------- gather (CSR) ----------
// MODE 0: out[i] = dinv[i]*(dinv[i]*xw[i] + sum_s dinv[s]*xw[s])   (GCN w/ self-loop)
// MODE 1: out[i] = wvec[i]*sum_s xw[s]                              (hypergraph halves)
template <int MODE>
__global__ void gather_k(const float* __restrict__ xw, float* __restrict__ out,
                         const int* __restrict__ offs, const int* __restrict__ cnt,
                         const int* __restrict__ slots, const float* __restrict__ wvec) {
  int node = blockIdx.x * 8 + (threadIdx.x >> 5);
  if (node >= NN) return;
  int c4 = threadIdx.x & 31;
  int st = offs[node], n = cnt[node];
  const float4* x4 = (const float4*)xw;
  float ax = 0.f, ay = 0.f, az = 0.f, aw = 0.f;
  for (int p = 0; p < n; ++p) {
    int s = slots[st + p];
    float4 v = x4[(size_t)s * 32 + c4];
    if (MODE == 0) {
      float f = wvec[s];
      ax = fmaf(f, v.x, ax); ay = fmaf(f, v.y, ay);
      az = fmaf(f, v.z, az); aw = fmaf(f, v.w, aw);
    } else {
      ax += v.x; ay += v.y; az += v.z; aw += v.w;
    }
  }
  float sc = wvec[node];
  float4 o;
  if (MODE == 0) {
    float4 self = x4[(size_t)node * 32 + c4];
    o.x = sc * fmaf(sc, self.x, ax);
    o.y = sc * fmaf(sc, self.y, ay);
    o.z = sc * fmaf(sc, self.z, az);
    o.w = sc * fmaf(sc, self.w, aw);
  } else {
    o.x = sc * ax; o.y = sc * ay; o.z = sc * az; o.w = sc * aw;
  }
  ((float4*)out)[(size_t)node * 32 + c4] = o;
}

// ---------- fuse(query-analytic, main) : one wave per row ----------
// hq = relu(s*Wq + bq); h = relu(g + bm); att = softmax([hq.aq, h.am]); out = att0*hq+att1*h
__global__ void fuse_qm(const float* __restrict__ g, const float* __restrict__ svec,
                        const float* __restrict__ dscale, const float* __restrict__ Wq,
                        const float* __restrict__ bq, const float* __restrict__ bm,
                        const float* __restrict__ aq, const float* __restrict__ am,
                        float* __restrict__ out) {
  int row = blockIdx.x * 4 + (threadIdx.x >> 6);
  if (row >= NN) return;
  int lane = threadIdx.x & 63;
  int c0 = lane, c1 = lane + 64;
  float s = svec[row];
  if (dscale) s *= dscale[row];
  float hq0 = fmaxf(fmaf(s, Wq[c0], bq[c0]), 0.f);
  float hq1 = fmaxf(fmaf(s, Wq[c1], bq[c1]), 0.f);
  float h0 = fmaxf(g[(size_t)row * 128 + c0] + bm[c0], 0.f);
  float h1 = fmaxf(g[(size_t)row * 128 + c1] + bm[c1], 0.f);
  float dq = wsum64(hq0 * aq[c0] + hq1 * aq[c1]);
  float dm = wsum64(h0 * am[c0] + h1 * am[c1]);
  float mx = fmaxf(dq, dm);
  float e0 = expf(dq - mx), e1 = expf(dm - mx);
  float w0 = e0 / (e0 + e1), w1 = 1.f - w0;
  out[(size_t)row * 128 + c0] = w0 * hq0 + w1 * h0;
  out[(size_t)row * 128 + c1] = w0 * hq1 + w1 * h1;
}

// ---------- fuse2: hf_ and hfh_ from querys2 (analytic) and feats2 ----------
__global__ void fuse2_k(const float* __restrict__ f2, const int* __restrict__ qp,
                        const float* __restrict__ Wlq, const float* __restrict__ blq,
                        const float* __restrict__ aq1, const float* __restrict__ a1,
                        const float* __restrict__ aq2, const float* __restrict__ a2,
                        float* __restrict__ out1, float* __restrict__ out2) {
  int row = blockIdx.x * 4 + (threadIdx.x >> 6);
  if (row >= NN) return;
  int lane = threadIdx.x & 63;
  int c0 = lane, c1 = lane + 64;
  int q = *qp;
  float q20 = blq[c0] + ((row == q) ? Wlq[c0] : 0.f);
  float q21 = blq[c1] + ((row == q) ? Wlq[c1] : 0.f);
  float f0 = f2[(size_t)row * 128 + c0];
  float f1 = f2[(size_t)row * 128 + c1];
  float dq1 = wsum64(q20 * aq1[c0] + q21 * aq1[c1]);
  float df1 = wsum64(f0 * a1[c0] + f1 * a1[c1]);
  float dq2 = wsum64(q20 * aq2[c0] + q21 * aq2[c1]);
  float df2 = wsum64(f0 * a2[c0] + f1 * a2[c1]);
  {
    float mx = fmaxf(dq1, df1);
    float e0 = expf(dq1 - mx), e1 = expf(df1 - mx);
    float w0 = e0 / (e0 + e1), w1 = 1.f - w0;
    out1[(size_t)row * 128 + c0] = w0 * q20 + w1 * f0;
    out1[(size_t)row * 128 + c1] = w0 * q21 + w1 * f1;
  }
  {
    float mx = fmaxf(dq2, df2);
    float e0 = expf(dq2 - mx), e1 = expf(df2 - mx);
    float w0 = e0 / (e0 + e1), w1 = 1.f - w0;
    out2[(size_t)row * 128 + c0] = w0 * q20 + w1 * f0;
    out2[(size_t)row * 128 + c1] = w0 * q21 + w1 * f1;
  }
}

// ---------- residual add + bias + relu (in place) ----------
__global__ void add_relu_k(float* __restrict__ acc, const float* __restrict__ g,
                           const float* __restrict__ bias, int total) {
  int i = blockIdx.x * 256 + threadIdx.x;
  if (i >= total) return;
  int c = i & 127;
  acc[i] = fmaxf(acc[i] + g[i] + bias[c], 0.f);
}

// ---------- similarity / loss accumulation: one wave per row ----------
__global__ void sim_k(const float* __restrict__ z, const float* __restrict__ za,
                      const int* __restrict__ qp, const int* __restrict__ maskI,
                      float* __restrict__ scal) {
  int row = blockIdx.x * 4 + (threadIdx.x >> 6);
  if (row >= NN) return;
  int lane = threadIdx.x & 63;
  int c0 = lane, c1 = lane + 64;
  int q = *qp;
  float zi0 = z[(size_t)row * 128 + c0], zi1 = z[(size_t)row * 128 + c1];
  float zai0 = za[(size_t)row * 128 + c0], zai1 = za[(size_t)row * 128 + c1];
  float zq0 = z[(size_t)q * 128 + c0], zq1 = z[(size_t)q * 128 + c1];
  float zaq0 = za[(size_t)q * 128 + c0], zaq1 = za[(size_t)q * 128 + c1];
  float nzi = wsum64(zi0 * zi0 + zi1 * zi1);
  float nzai = wsum64(zai0 * zai0 + zai1 * zai1);
  float nzq = wsum64(zq0 * zq0 + zq1 * zq1);
  float nzaq = wsum64(zaq0 * zaq0 + zaq1 * zaq1);
  float d1 = wsum64(zi0 * zq0 + zi1 * zq1);     // z_i . zq
  float d2 = wsum64(zai0 * zaq0 + zai1 * zaq1); // za_i . zaq
  float d3 = wsum64(zai0 * zq0 + zai1 * zq1);   // za_i . zq
  float d4 = wsum64(zi0 * zaq0 + zi1 * zaq1);   // z_i . zaq
  if (lane == 0) {
    float ni = sqrtf(nzi), nai = sqrtf(nzai), nq = sqrtf(nzq), naq = sqrtf(nzaq);
    float c1_ = d1 / fmaxf(ni * nq, 1e-8f) * TAU_INV;    // log sim1_i
    float ca1 = d2 / fmaxf(nai * naq, 1e-8f) * TAU_INV;  // log sim_aug1_i
    float c2_ = d3 / fmaxf(nai * nq, 1e-8f) * TAU_INV;   // log sim2_i
    float ca2 = d4 / fmaxf(ni * naq, 1e-8f) * TAU_INV;   // log sim_aug2_i
    atomicAdd(&scal[0], expf(c1_));
    atomicAdd(&scal[1], expf(ca1));
    atomicAdd(&scal[2], expf(c2_));
    atomicAdd(&scal[3], expf(ca2));
    if (maskI[row]) {
      atomicAdd(&scal[4], c1_);
      atomicAdd(&scal[5], ca1);
      atomicAdd(&scal[6], c2_);
      atomicAdd(&scal[7], ca2);
      atomicAdd(&scal[8], 1.0f);
    }
    if (row == q) {
      scal[9] = c2_;
      scal[10] = ca2;
    }
  }
}

__global__ void final_k(const float* __restrict__ scal, float* __restrict__ out) {
  if (threadIdx.x != 0 || blockIdx.x != 0) return;
  float S1 = scal[0], Sa1 = scal[1], S2 = scal[2], Sa2 = scal[3];
  float L1 = scal[4], La1 = scal[5], L2 = scal[6], La2 = scal[7];
  float NM = scal[8], Q2 = scal[9], Qa2 = scal[10];
  float intra = 0.5f * ((logf(S1) - L1 / NM) + (logf(Sa1) - La1 / NM));
  float inter = 0.5f * ((logf(S2) - L2 / NM) + (logf(Sa2) - La2 / NM));
  float unsup = 0.5f * (logf(S2) - Q2) + 0.5f * (logf(Sa2) - Qa2);
  out[0] = intra + 0.5f * inter + 0.5f * unsup;  // ALPHA=0.5, LAM=0.5
}

// ---------- host ----------
extern "C" void kernel_launch(void* const* d_in, const int* in_sizes, int n_in,
                              void* d_out, int out_size, void* d_ws, size_t ws_size,
                              hipStream_t stream) {
  const float* feats = (const float*)d_in[0];
  const int* ei = (const int*)d_in[1];
  const int* ea = (const int*)d_in[2];
  const int* pos = (const int*)d_in[3];
  const int* qp = (const int*)d_in[4];
  const float* Wq0 = (const float*)d_in[5];
  const float* bq0 = (const float*)d_in[6];
  const float* W0 = (const float*)d_in[7];
  const float* b0 = (const float*)d_in[8];
  const float* Whq0 = (const float*)d_in[9];
  const float* bhq0 = (const float*)d_in[10];
  const float* Wh0 = (const float*)d_in[11];
  const float* bh0 = (const float*)d_in[12];
  const float* Wf0 = (const float*)d_in[13];
  const float* bf0 = (const float*)d_in[14];
  const float* Wfh0 = (const float*)d_in[15];
  const float* bfh0 = (const float*)d_in[16];
  const float* aq0 = (const float*)d_in[17];
  const float* a0 = (const float*)d_in[18];
  const float* ahq0 = (const float*)d_in[19];
  const float* ah0 = (const float*)d_in[20];
  const float* aq_ = (const float*)d_in[21];
  const float* a_ = (const float*)d_in[22];
  const float* ahq_ = (const float*)d_in[23];
  const float* ah_ = (const float*)d_in[24];
  const float* Wlq = (const float*)d_in[25];
  const float* blq = (const float*)d_in[26];
  const float* Wlf = (const float*)d_in[27];
  const float* blf = (const float*)d_in[28];
  const float* Wm1 = (const float*)d_in[29];
  const float* bm1 = (const float*)d_in[30];
  const float* Wm2 = (const float*)d_in[31];
  const float* bm2 = (const float*)d_in[32];

  char* ws = (char*)d_ws;
  size_t off = 0;
  auto take = [&](size_t bytes) -> void* {
    void* p = ws + off;
    off = (off + bytes + 255) & ~(size_t)255;
    return p;
  };
  // ---- zero region (one memset) ----
  int* cnt3 = (int*)take(3 * NN * 4);
  int* cursor3 = (int*)take(3 * NN * 4);
  int* aux = (int*)take(1024 * 4);
  int* maskI = (int*)take(NN * 4);
  float* s_hq = (float*)take(NN * 4);
  float* cntq = (float*)take(NN * 4);
  float* s_hgq = (float*)take(NN * 4);
  float* scal = (float*)take(64 * 4);
  size_t zero_end = off;
  // ---- non-zeroed scratch ----
  int* offs3 = (int*)take(3 * NN * 4);
  int* slots = (int*)take((size_t)3 * EE * 4);
  float* dinv = (float*)take(NN * 4);
  float* Binv = (float*)take(NN * 4);
  float* Dninv = (float*)take(NN * 4);
  float* bufA = (float*)take((size_t)NN * HH * 4);
  float* bufB = (float*)take((size_t)NN * HH * 4);
  float* bufC = (float*)take((size_t)NN * HH * 4);
  float* bufD = (float*)take((size_t)NN * HH * 4);
  float* bufF2 = (float*)take((size_t)NN * HH * 4);

  const int EB = (EE + 255) / 256;
  const int NB = (NN + 255) / 256;
  const int M3 = 3 * NN;
  const int SB = (M3 + 255) / 256;
  const int GB = (NN + 63) / 64;
  const int GTB = (NN + 7) / 8;
  const int RB = (NN + 3) / 4;
  const int AB = (NN * HH + 255) / 256;

  hipMemsetAsync(d_ws, 0, zero_end, stream);
  // CSR build + degree vectors
  count_k<<<EB, 256, 0, stream>>>(ei, ea, qp, cnt3, cntq);
  derive_k<<<NB, 256, 0, stream>>>(cnt3, dinv, Binv, Dninv);
  scan1<<<SB, 256, 0, stream>>>(cnt3, offs3, aux, M3);
  scan2<<<1, 1024, 0, stream>>>(aux, SB);
  scan3<<<SB, 256, 0, stream>>>(offs3, aux, M3);
  fill_k<<<EB, 256, 0, stream>>>(ei, ea, offs3, cursor3, slots);
  // analytic query coefficients + mask
  shq_k<<<EB, 256, 0, stream>>>(ei, ea, qp, dinv, Binv, cntq, s_hq, s_hgq);
  mask_k<<<1, 128, 0, stream>>>(pos, qp, maskI, s_hq, dinv);

  // feats2 = feats@Wlf + blf
  gemm128<true, false><<<GB, 256, 0, stream>>>(feats, Wlf, blf, bufF2, NN);
  // GCN(feats): xw -> gather -> fuse with analytic hq => hf (bufC)
  gemm128<false, false><<<GB, 256, 0, stream>>>(feats, W0, nullptr, bufA, NN);
  gather_k<0><<<GTB, 256, 0, stream>>>(bufA, bufB, offs3, cnt3, slots, dinv);
  fuse_qm<<<RB, 256, 0, stream>>>(bufB, s_hq, nullptr, Wq0, bq0, b0, aq0, a0, bufC);
  // HG(feats): xw -> gather(he) -> gather(node) -> fuse => h_augf (bufD)
  gemm128<false, false><<<GB, 256, 0, stream>>>(feats, Wh0, nullptr, bufA, NN);
  gather_k<1><<<GTB, 256, 0, stream>>>(bufA, bufB, offs3 + NN, cnt3 + NN, slots, Binv);
  gather_k<1><<<GTB, 256, 0, stream>>>(bufB, bufA, offs3 + 2 * NN, cnt3 + 2 * NN, slots, Dninv);
  fuse_qm<<<RB, 256, 0, stream>>>(bufA, s_hgq, Dninv, Whq0, bhq0, bh0, ahq0, ah0, bufD);
  // hf_ (bufA), hfh_ (bufB)
  fuse2_k<<<RB, 256, 0, stream>>>(bufF2, qp, Wlq, blq, aq_, a_, ahq_, ah_, bufA, bufB);
  // hf = relu(hf + gcn(hf_, Wf0, bf0))
  gemm128<false, false><<<GB, 256, 0, stream>>>(bufA, Wf0, nullptr, bufF2, NN);
  gather_k<0><<<GTB, 256, 0, stream>>>(bufF2, bufA, offs3, cnt3, slots, dinv);
  add_relu_k<<<AB, 256, 0, stream>>>(bufC, bufA, bf0, NN * HH);
  // h_augf = relu(h_augf + hg(hfh_, Wfh0, bfh0))
  gemm128<false, false><<<GB, 256, 0, stream>>>(bufB, Wfh0, nullptr, bufF2, NN);
  gather_k<1><<<GTB, 256, 0, stream>>>(bufF2, bufA, offs3 + NN, cnt3 + NN, slots, Binv);
  gather_k<1><<<GTB, 256, 0, stream>>>(bufA, bufF2, offs3 + 2 * NN, cnt3 + 2 * NN, slots, Dninv);
  add_relu_k<<<AB, 256, 0, stream>>>(bufD, bufF2, bfh0, NN * HH);
  // MLPs: z = relu(hf@Wm1+bm1)@Wm2+bm2 ; z_aug likewise
  gemm128<true, true><<<GB, 256, 0, stream>>>(bufC, Wm1, bm1, bufA, NN);
  gemm128<true, false><<<GB, 256, 0, stream>>>(bufA, Wm2, bm2, bufB, NN);  // z
  gemm128<true, true><<<GB, 256, 0, stream>>>(bufD, Wm1, bm1, bufA, NN);
  gemm128<true, false><<<GB, 256, 0, stream>>>(bufA, Wm2, bm2, bufF2, NN); // z_aug
  // loss
  sim_k<<<RB, 256, 0, stream>>>(bufB, bufF2, qp, maskI, scal);
  final_k<<<1, 64, 0, stream>>>(scal, (float*)d_out);
}

// Round 2
// 1093.215 us; speedup vs baseline: 3.3271x; 3.3271x over previous
//
#include <hip/hip_runtime.h>

#define NN 50000
#define EE 600000
#define HH 128
#define TAU_INV 2.0f   // 1/TAU, TAU=0.5

// ---------- helpers ----------
__device__ __forceinline__ float wsum64(float v) {
#pragma unroll
  for (int m = 32; m >= 1; m >>= 1) v += __shfl_xor(v, m, 64);
  return v;
}

// ---------- CSR build ----------
__global__ void count_k(const int* __restrict__ ei, const int* __restrict__ ea,
                        const int* __restrict__ qp, int* __restrict__ cnt,
                        float* __restrict__ cntq) {
  int e = blockIdx.x * 256 + threadIdx.x;
  if (e >= EE) return;
  int q = *qp;
  int dst = ei[EE + e];
  atomicAdd(&cnt[dst], 1);
  int node = ea[e], he = ea[EE + e];
  atomicAdd(&cnt[NN + he], 1);
  atomicAdd(&cnt[2 * NN + node], 1);
  if (node == q) atomicAdd(&cntq[he], 1.0f);
}

__global__ void derive_k(const int* __restrict__ cnt, float* __restrict__ dinv,
                         float* __restrict__ Binv, float* __restrict__ Dninv) {
  int i = blockIdx.x * 256 + threadIdx.x;
  if (i >= NN) return;
  dinv[i] = rsqrtf((float)(cnt[i] + 1));          // deg includes self-loop
  int b = cnt[NN + i];
  Binv[i] = (b > 0) ? 1.0f / (float)b : 0.0f;
  int d = cnt[2 * NN + i];
  Dninv[i] = (d > 0) ? 1.0f / (float)d : 0.0f;
}

__global__ void scan1(const int* __restrict__ cnt, int* __restrict__ offs,
                      int* __restrict__ aux, int M) {
  __shared__ int s[256];
  int tid = threadIdx.x, gid = blockIdx.x * 256 + tid;
  int v = (gid < M) ? cnt[gid] : 0;
  s[tid] = v;
  __syncthreads();
  for (int d = 1; d < 256; d <<= 1) {
    int t = (tid >= d) ? s[tid - d] : 0;
    __syncthreads();
    s[tid] += t;
    __syncthreads();
  }
  if (gid < M) offs[gid] = s[tid] - v;  // exclusive
  if (tid == 255) aux[blockIdx.x] = s[255];
}

__global__ void scan2(int* __restrict__ aux, int nb) {
  __shared__ int s[1024];
  int tid = threadIdx.x;
  int v = (tid < nb) ? aux[tid] : 0;
  s[tid] = v;
  __syncthreads();
  for (int d = 1; d < 1024; d <<= 1) {
    int t = (tid >= d) ? s[tid - d] : 0;
    __syncthreads();
    s[tid] += t;
    __syncthreads();
  }
  if (tid < nb) aux[tid] = s[tid] - v;  // exclusive over block sums
}

__global__ void scan3(int* __restrict__ offs, const int* __restrict__ aux, int M) {
  int gid = blockIdx.x * 256 + threadIdx.x;
  if (gid < M) offs[gid] += aux[blockIdx.x];
}

__global__ void fill_k(const int* __restrict__ ei, const int* __restrict__ ea,
                       const int* __restrict__ offs, int* __restrict__ cursor,
                       int* __restrict__ slots) {
  int e = blockIdx.x * 256 + threadIdx.x;
  if (e >= EE) return;
  int src = ei[e], dst = ei[EE + e];
  int p = offs[dst] + atomicAdd(&cursor[dst], 1);
  slots[p] = src;
  int node = ea[e], he = ea[EE + e];
  int p2 = offs[NN + he] + atomicAdd(&cursor[NN + he], 1);
  slots[p2] = node;
  int p3 = offs[2 * NN + node] + atomicAdd(&cursor[2 * NN + node], 1);
  slots[p3] = he;
}

// ---------- analytic query-column coefficients ----------
__global__ void shq_k(const int* __restrict__ ei, const int* __restrict__ ea,
                      const int* __restrict__ qp, const float* __restrict__ dinv,
                      const float* __restrict__ Binv, const float* __restrict__ cntq,
                      float* __restrict__ s_hq, float* __restrict__ s_hgq) {
  int e = blockIdx.x * 256 + threadIdx.x;
  if (e >= EE) return;
  int q = *qp;
  int src = ei[e], dst = ei[EE + e];
  if (src == q) atomicAdd(&s_hq[dst], dinv[q] * dinv[dst]);
  int node = ea[e], he = ea[EE + e];
  float t = Binv[he] * cntq[he];
  if (t != 0.0f) atomicAdd(&s_hgq[node], t);
}

__global__ void mask_k(const int* __restrict__ pos, const int* __restrict__ qp,
                       int* __restrict__ maskI, float* __restrict__ s_hq,
                       const float* __restrict__ dinv) {
  int t = threadIdx.x;
  if (t < 100) maskI[pos[t]] = 1;
  __syncthreads();
  if (t == 0) {
    int q = *qp;
    maskI[q] = 0;
    s_hq[q] += dinv[q] * dinv[q];  // self-loop contribution of the query gcn
  }
}

// ---------- GEMM: C[N,128] = op(A[N,128] @ W[128,128] (+bias)) ----------
template <bool BIAS, bool RELU>
__global__ __launch_bounds__(256) void gemm128(const float* __restrict__ A,
                                               const float* __restrict__ W,
                                               const float* __restrict__ bias,
                                               float* __restrict__ C, int nrows) {
  __shared__ float As[64 * 128];
  const int tid = threadIdx.x;
  const int r0 = blockIdx.x * 64;
  {
    const float4* A4 = (const float4*)A;
    float4* As4 = (float4*)As;
#pragma unroll
    for (int t = 0; t < 8; ++t) {
      int v = t * 256 + tid;
      int row = v >> 5, c4 = v & 31;
      int gr = r0 + row;
      float4 val = make_float4(0.f, 0.f, 0.f, 0.f);
      if (gr < nrows) val = A4[(size_t)gr * 32 + c4];
      As4[v] = val;
    }
  }
  __syncthreads();
  const int tx = tid & 15, ty = tid >> 4;
  const int cb = tx * 8, rb = ty * 4;
  float acc[4][8];
#pragma unroll
  for (int i = 0; i < 4; ++i)
#pragma unroll
    for (int j = 0; j < 8; ++j) acc[i][j] = 0.f;
  const float4* W4 = (const float4*)W;
  for (int k = 0; k < 128; k += 4) {
    float a[4][4];
#pragma unroll
    for (int i = 0; i < 4; ++i) {
      float4 t4 = *(const float4*)&As[(rb + i) * 128 + k];
      a[i][0] = t4.x; a[i][1] = t4.y; a[i][2] = t4.z; a[i][3] = t4.w;
    }
#pragma unroll
    for (int kk = 0; kk < 4; ++kk) {
      float4 w0 = W4[(k + kk) * 32 + (cb >> 2)];
      float4 w1 = W4[(k + kk) * 32 + (cb >> 2) + 1];
      float wv[8] = {w0.x, w0.y, w0.z, w0.w, w1.x, w1.y, w1.z, w1.w};
#pragma unroll
      for (int i = 0; i < 4; ++i)
#pragma unroll
        for (int j = 0; j < 8; ++j) acc[i][j] = fmaf(a[i][kk], wv[j], acc[i][j]);
    }
  }
#pragma unroll
  for (int i = 0; i < 4; ++i) {
    int gr = r0 + rb + i;
    if (gr >= nrows) continue;
#pragma unroll
    for (int j = 0; j < 8; j += 4) {
      float o[4];
#pragma unroll
      for (int jj = 0; jj < 4; ++jj) {
        float v = acc[i][j + jj];
        if (BIAS) v += bias[cb + j + jj];
        if (RELU) v = fmaxf(v, 0.f);
        o[jj] = v;
      }
      *(float4*)&C[(size_t)gr * 128 + cb + j] = make_float4(o[0], o[1], o[2], o[3]);
    }
  }
}

// ---------- gather (CSR) ----------
// MODE 0: out[i] = dinv[i]*(dinv[i]*xw[i] + sum_s dinv[s]*xw[s])   (GCN w/ self-loop)
// MODE 1: out[i] = wvec[i]*sum_s xw[s]                              (hypergraph halves)
template <int MODE>
__global__ void gather_k(const float* __restrict__ xw, float* __restrict__ out,
                         const int* __restrict__ offs, const int* __restrict__ cnt,
                         const int* __restrict__ slots, const float* __restrict__ wvec) {
  int node = blockIdx.x * 8 + (threadIdx.x >> 5);
  if (node >= NN) return;
  int c4 = threadIdx.x & 31;
  int st = offs[node], n = cnt[node];
  const float4* x4 = (const float4*)xw;
  float ax = 0.f, ay = 0.f, az = 0.f, aw = 0.f;
  for (int p = 0; p < n; ++p) {
    int s = slots[st + p];
    float4 v = x4[(size_t)s * 32 + c4];
    if (MODE == 0) {
      float f = wvec[s];
      ax = fmaf(f, v.x, ax); ay = fmaf(f, v.y, ay);
      az = fmaf(f, v.z, az); aw = fmaf(f, v.w, aw);
    } else {
      ax += v.x; ay += v.y; az += v.z; aw += v.w;
    }
  }
  float sc = wvec[node];
  float4 o;
  if (MODE == 0) {
    float4 self = x4[(size_t)node * 32 + c4];
    o.x = sc * fmaf(sc, self.x, ax);
    o.y = sc * fmaf(sc, self.y, ay);
    o.z = sc * fmaf(sc, self.z, az);
    o.w = sc * fmaf(sc, self.w, aw);
  } else {
    o.x = sc * ax; o.y = sc * ay; o.z = sc * az; o.w = sc * aw;
  }
  ((float4*)out)[(size_t)node * 32 + c4] = o;
}

// ---------- fuse(query-analytic, main) : one wave per row ----------
__global__ void fuse_qm(const float* __restrict__ g, const float* __restrict__ svec,
                        const float* __restrict__ dscale, const float* __restrict__ Wq,
                        const float* __restrict__ bq, const float* __restrict__ bm,
                        const float* __restrict__ aq, const float* __restrict__ am,
                        float* __restrict__ out) {
  int row = blockIdx.x * 4 + (threadIdx.x >> 6);
  if (row >= NN) return;
  int lane = threadIdx.x & 63;
  int c0 = lane, c1 = lane + 64;
  float s = svec[row];
  if (dscale) s *= dscale[row];
  float hq0 = fmaxf(fmaf(s, Wq[c0], bq[c0]), 0.f);
  float hq1 = fmaxf(fmaf(s, Wq[c1], bq[c1]), 0.f);
  float h0 = fmaxf(g[(size_t)row * 128 + c0] + bm[c0], 0.f);
  float h1 = fmaxf(g[(size_t)row * 128 + c1] + bm[c1], 0.f);
  float dq = wsum64(hq0 * aq[c0] + hq1 * aq[c1]);
  float dm = wsum64(h0 * am[c0] + h1 * am[c1]);
  float mx = fmaxf(dq, dm);
  float e0 = expf(dq - mx), e1 = expf(dm - mx);
  float w0 = e0 / (e0 + e1), w1 = 1.f - w0;
  out[(size_t)row * 128 + c0] = w0 * hq0 + w1 * h0;
  out[(size_t)row * 128 + c1] = w0 * hq1 + w1 * h1;
}

// ---------- fuse2: hf_ and hfh_ from querys2 (analytic) and feats2 ----------
__global__ void fuse2_k(const float* __restrict__ f2, const int* __restrict__ qp,
                        const float* __restrict__ Wlq, const float* __restrict__ blq,
                        const float* __restrict__ aq1, const float* __restrict__ a1,
                        const float* __restrict__ aq2, const float* __restrict__ a2,
                        float* __restrict__ out1, float* __restrict__ out2) {
  int row = blockIdx.x * 4 + (threadIdx.x >> 6);
  if (row >= NN) return;
  int lane = threadIdx.x & 63;
  int c0 = lane, c1 = lane + 64;
  int q = *qp;
  float q20 = blq[c0] + ((row == q) ? Wlq[c0] : 0.f);
  float q21 = blq[c1] + ((row == q) ? Wlq[c1] : 0.f);
  float f0 = f2[(size_t)row * 128 + c0];
  float f1 = f2[(size_t)row * 128 + c1];
  float dq1 = wsum64(q20 * aq1[c0] + q21 * aq1[c1]);
  float df1 = wsum64(f0 * a1[c0] + f1 * a1[c1]);
  float dq2 = wsum64(q20 * aq2[c0] + q21 * aq2[c1]);
  float df2 = wsum64(f0 * a2[c0] + f1 * a2[c1]);
  {
    float mx = fmaxf(dq1, df1);
    float e0 = expf(dq1 - mx), e1 = expf(df1 - mx);
    float w0 = e0 / (e0 + e1), w1 = 1.f - w0;
    out1[(size_t)row * 128 + c0] = w0 * q20 + w1 * f0;
    out1[(size_t)row * 128 + c1] = w0 * q21 + w1 * f1;
  }
  {
    float mx = fmaxf(dq2, df2);
    float e0 = expf(dq2 - mx), e1 = expf(df2 - mx);
    float w0 = e0 / (e0 + e1), w1 = 1.f - w0;
    out2[(size_t)row * 128 + c0] = w0 * q20 + w1 * f0;
    out2[(size_t)row * 128 + c1] = w0 * q21 + w1 * f1;
  }
}

// ---------- residual add + bias + relu (in place) ----------
__global__ void add_relu_k(float* __restrict__ acc, const float* __restrict__ g,
                           const float* __restrict__ bias, int total) {
  int i = blockIdx.x * 256 + threadIdx.x;
  if (i >= total) return;
  int c = i & 127;
  acc[i] = fmaxf(acc[i] + g[i] + bias[c], 0.f);
}

// ---------- q-row norms: one wave ----------
__global__ void qnorm_k(const float* __restrict__ z, const float* __restrict__ za,
                        const int* __restrict__ qp, float* __restrict__ scal) {
  int lane = threadIdx.x & 63;
  int q = *qp;
  float zq0 = z[(size_t)q * 128 + lane], zq1 = z[(size_t)q * 128 + lane + 64];
  float zaq0 = za[(size_t)q * 128 + lane], zaq1 = za[(size_t)q * 128 + lane + 64];
  float nq = wsum64(zq0 * zq0 + zq1 * zq1);
  float naq = wsum64(zaq0 * zaq0 + zaq1 * zaq1);
  if (lane == 0) {
    scal[11] = sqrtf(nq);
    scal[12] = sqrtf(naq);
  }
}

// ---------- per-row cosine logits (no atomics) ----------
__global__ void sim_k(const float* __restrict__ z, const float* __restrict__ za,
                      const int* __restrict__ qp, const float* __restrict__ scal,
                      float4* __restrict__ simbuf, float* __restrict__ scal_out) {
  int row = blockIdx.x * 4 + (threadIdx.x >> 6);
  if (row >= NN) return;
  int lane = threadIdx.x & 63;
  int c0 = lane, c1 = lane + 64;
  int q = *qp;
  float zi0 = z[(size_t)row * 128 + c0], zi1 = z[(size_t)row * 128 + c1];
  float zai0 = za[(size_t)row * 128 + c0], zai1 = za[(size_t)row * 128 + c1];
  float zq0 = z[(size_t)q * 128 + c0], zq1 = z[(size_t)q * 128 + c1];
  float zaq0 = za[(size_t)q * 128 + c0], zaq1 = za[(size_t)q * 128 + c1];
  float nzi = wsum64(zi0 * zi0 + zi1 * zi1);
  float nzai = wsum64(zai0 * zai0 + zai1 * zai1);
  float d1 = wsum64(zi0 * zq0 + zi1 * zq1);     // z_i . zq
  float d2 = wsum64(zai0 * zaq0 + zai1 * zaq1); // za_i . zaq
  float d3 = wsum64(zai0 * zq0 + zai1 * zq1);   // za_i . zq
  float d4 = wsum64(zi0 * zaq0 + zi1 * zaq1);   // z_i . zaq
  if (lane == 0) {
    float ni = sqrtf(nzi), nai = sqrtf(nzai);
    float nq = scal[11], naq = scal[12];
    float c1_ = d1 / fmaxf(ni * nq, 1e-8f) * TAU_INV;    // log sim1_i
    float ca1 = d2 / fmaxf(nai * naq, 1e-8f) * TAU_INV;  // log sim_aug1_i
    float c2_ = d3 / fmaxf(nai * nq, 1e-8f) * TAU_INV;   // log sim2_i
    float ca2 = d4 / fmaxf(ni * naq, 1e-8f) * TAU_INV;   // log sim_aug2_i
    simbuf[row] = make_float4(c1_, ca1, c2_, ca2);
    if (row == q) {
      scal_out[9] = c2_;
      scal_out[10] = ca2;
    }
  }
}

// ---------- two-stage reduction over simbuf ----------
__global__ __launch_bounds__(256) void reduce_sim_k(const float4* __restrict__ simbuf,
                                                    const int* __restrict__ maskI,
                                                    float* __restrict__ scal) {
  float acc[9];
#pragma unroll
  for (int i = 0; i < 9; ++i) acc[i] = 0.f;
  for (int row = blockIdx.x * 256 + threadIdx.x; row < NN; row += gridDim.x * 256) {
    float4 v = simbuf[row];
    acc[0] += expf(v.x);
    acc[1] += expf(v.y);
    acc[2] += expf(v.z);
    acc[3] += expf(v.w);
    if (maskI[row]) {
      acc[4] += v.x; acc[5] += v.y; acc[6] += v.z; acc[7] += v.w;
      acc[8] += 1.0f;
    }
  }
  __shared__ float s[9][4];
  int lane = threadIdx.x & 63, wv = threadIdx.x >> 6;
#pragma unroll
  for (int i = 0; i < 9; ++i) {
    float r = wsum64(acc[i]);
    if (lane == 0) s[i][wv] = r;
  }
  __syncthreads();
  if (threadIdx.x < 9) {
    float r = s[threadIdx.x][0] + s[threadIdx.x][1] + s[threadIdx.x][2] + s[threadIdx.x][3];
    atomicAdd(&scal[threadIdx.x], r);
  }
}

__global__ void final_k(const float* __restrict__ scal, float* __restrict__ out) {
  if (threadIdx.x != 0 || blockIdx.x != 0) return;
  float S1 = scal[0], Sa1 = scal[1], S2 = scal[2], Sa2 = scal[3];
  float L1 = scal[4], La1 = scal[5], L2 = scal[6], La2 = scal[7];
  float NM = scal[8], Q2 = scal[9], Qa2 = scal[10];
  float intra = 0.5f * ((logf(S1) - L1 / NM) + (logf(Sa1) - La1 / NM));
  float inter = 0.5f * ((logf(S2) - L2 / NM) + (logf(Sa2) - La2 / NM));
  float unsup = 0.5f * (logf(S2) - Q2) + 0.5f * (logf(Sa2) - Qa2);
  out[0] = intra + 0.5f * inter + 0.5f * unsup;  // ALPHA=0.5, LAM=0.5
}

// ---------- host ----------
extern "C" void kernel_launch(void* const* d_in, const int* in_sizes, int n_in,
                              void* d_out, int out_size, void* d_ws, size_t ws_size,
                              hipStream_t stream) {
  const float* feats = (const float*)d_in[0];
  const int* ei = (const int*)d_in[1];
  const int* ea = (const int*)d_in[2];
  const int* pos = (const int*)d_in[3];
  const int* qp = (const int*)d_in[4];
  const float* Wq0 = (const float*)d_in[5];
  const float* bq0 = (const float*)d_in[6];
  const float* W0 = (const float*)d_in[7];
  const float* b0 = (const float*)d_in[8];
  const float* Whq0 = (const float*)d_in[9];
  const float* bhq0 = (const float*)d_in[10];
  const float* Wh0 = (const float*)d_in[11];
  const float* bh0 = (const float*)d_in[12];
  const float* Wf0 = (const float*)d_in[13];
  const float* bf0 = (const float*)d_in[14];
  const float* Wfh0 = (const float*)d_in[15];
  const float* bfh0 = (const float*)d_in[16];
  const float* aq0 = (const float*)d_in[17];
  const float* a0 = (const float*)d_in[18];
  const float* ahq0 = (const float*)d_in[19];
  const float* ah0 = (const float*)d_in[20];
  const float* aq_ = (const float*)d_in[21];
  const float* a_ = (const float*)d_in[22];
  const float* ahq_ = (const float*)d_in[23];
  const float* ah_ = (const float*)d_in[24];
  const float* Wlq = (const float*)d_in[25];
  const float* blq = (const float*)d_in[26];
  const float* Wlf = (const float*)d_in[27];
  const float* blf = (const float*)d_in[28];
  const float* Wm1 = (const float*)d_in[29];
  const float* bm1 = (const float*)d_in[30];
  const float* Wm2 = (const float*)d_in[31];
  const float* bm2 = (const float*)d_in[32];

  char* ws = (char*)d_ws;
  size_t off = 0;
  auto take = [&](size_t bytes) -> void* {
    void* p = ws + off;
    off = (off + bytes + 255) & ~(size_t)255;
    return p;
  };
  // ---- zero region (one memset) ----
  int* cnt3 = (int*)take(3 * NN * 4);
  int* cursor3 = (int*)take(3 * NN * 4);
  int* aux = (int*)take(1024 * 4);
  int* maskI = (int*)take(NN * 4);
  float* s_hq = (float*)take(NN * 4);
  float* cntq = (float*)take(NN * 4);
  float* s_hgq = (float*)take(NN * 4);
  float* scal = (float*)take(64 * 4);
  size_t zero_end = off;
  // ---- non-zeroed scratch ----
  int* offs3 = (int*)take(3 * NN * 4);
  int* slots = (int*)take((size_t)3 * EE * 4);
  float* dinv = (float*)take(NN * 4);
  float* Binv = (float*)take(NN * 4);
  float* Dninv = (float*)take(NN * 4);
  float4* simbuf = (float4*)take((size_t)NN * 16);
  float* bufA = (float*)take((size_t)NN * HH * 4);
  float* bufB = (float*)take((size_t)NN * HH * 4);
  float* bufC = (float*)take((size_t)NN * HH * 4);
  float* bufD = (float*)take((size_t)NN * HH * 4);
  float* bufF2 = (float*)take((size_t)NN * HH * 4);

  const int EB = (EE + 255) / 256;
  const int NB = (NN + 255) / 256;
  const int M3 = 3 * NN;
  const int SB = (M3 + 255) / 256;
  const int GB = (NN + 63) / 64;
  const int GTB = (NN + 7) / 8;
  const int RB = (NN + 3) / 4;
  const int AB = (NN * HH + 255) / 256;

  hipMemsetAsync(d_ws, 0, zero_end, stream);
  // CSR build + degree vectors
  count_k<<<EB, 256, 0, stream>>>(ei, ea, qp, cnt3, cntq);
  derive_k<<<NB, 256, 0, stream>>>(cnt3, dinv, Binv, Dninv);
  scan1<<<SB, 256, 0, stream>>>(cnt3, offs3, aux, M3);
  scan2<<<1, 1024, 0, stream>>>(aux, SB);
  scan3<<<SB, 256, 0, stream>>>(offs3, aux, M3);
  fill_k<<<EB, 256, 0, stream>>>(ei, ea, offs3, cursor3, slots);
  // analytic query coefficients + mask
  shq_k<<<EB, 256, 0, stream>>>(ei, ea, qp, dinv, Binv, cntq, s_hq, s_hgq);
  mask_k<<<1, 128, 0, stream>>>(pos, qp, maskI, s_hq, dinv);

  // feats2 = feats@Wlf + blf
  gemm128<true, false><<<GB, 256, 0, stream>>>(feats, Wlf, blf, bufF2, NN);
  // GCN(feats): xw -> gather -> fuse with analytic hq => hf (bufC)
  gemm128<false, false><<<GB, 256, 0, stream>>>(feats, W0, nullptr, bufA, NN);
  gather_k<0><<<GTB, 256, 0, stream>>>(bufA, bufB, offs3, cnt3, slots, dinv);
  fuse_qm<<<RB, 256, 0, stream>>>(bufB, s_hq, nullptr, Wq0, bq0, b0, aq0, a0, bufC);
  // HG(feats): xw -> gather(he) -> gather(node) -> fuse => h_augf (bufD)
  gemm128<false, false><<<GB, 256, 0, stream>>>(feats, Wh0, nullptr, bufA, NN);
  gather_k<1><<<GTB, 256, 0, stream>>>(bufA, bufB, offs3 + NN, cnt3 + NN, slots, Binv);
  gather_k<1><<<GTB, 256, 0, stream>>>(bufB, bufA, offs3 + 2 * NN, cnt3 + 2 * NN, slots, Dninv);
  fuse_qm<<<RB, 256, 0, stream>>>(bufA, s_hgq, Dninv, Whq0, bhq0, bh0, ahq0, ah0, bufD);
  // hf_ (bufA), hfh_ (bufB)
  fuse2_k<<<RB, 256, 0, stream>>>(bufF2, qp, Wlq, blq, aq_, a_, ahq_, ah_, bufA, bufB);
  // hf = relu(hf + gcn(hf_, Wf0, bf0))
  gemm128<false, false><<<GB, 256, 0, stream>>>(bufA, Wf0, nullptr, bufF2, NN);
  gather_k<0><<<GTB, 256, 0, stream>>>(bufF2, bufA, offs3, cnt3, slots, dinv);
  add_relu_k<<<AB, 256, 0, stream>>>(bufC, bufA, bf0, NN * HH);
  // h_augf = relu(h_augf + hg(hfh_, Wfh0, bfh0))
  gemm128<false, false><<<GB, 256, 0, stream>>>(bufB, Wfh0, nullptr, bufF2, NN);
  gather_k<1><<<GTB, 256, 0, stream>>>(bufF2, bufA, offs3 + NN, cnt3 + NN, slots, Binv);
  gather_k<1><<<GTB, 256, 0, stream>>>(bufA, bufF2, offs3 + 2 * NN, cnt3 + 2 * NN, slots, Dninv);
  add_relu_k<<<AB, 256, 0, stream>>>(bufD, bufF2, bfh0, NN * HH);
  // MLPs: z = relu(hf@Wm1+bm1)@Wm2+bm2 ; z_aug likewise
  gemm128<true, true><<<GB, 256, 0, stream>>>(bufC, Wm1, bm1, bufA, NN);
  gemm128<true, false><<<GB, 256, 0, stream>>>(bufA, Wm2, bm2, bufB, NN);  // z
  gemm128<true, true><<<GB, 256, 0, stream>>>(bufD, Wm1, bm1, bufA, NN);
  gemm128<true, false><<<GB, 256, 0, stream>>>(bufA, Wm2, bm2, bufF2, NN); // z_aug
  // loss
  qnorm_k<<<1, 64, 0, stream>>>(bufB, bufF2, qp, scal);
  sim_k<<<RB, 256, 0, stream>>>(bufB, bufF2, qp, scal, simbuf, scal);
  reduce_sim_k<<<64, 256, 0, stream>>>(simbuf, maskI, scal);
  final_k<<<1, 64, 0, stream>>>(scal, (float*)d_out);
}

// Round 3
// 664.250 us; speedup vs baseline: 5.4758x; 1.6458x over previous
//
#include <hip/hip_runtime.h>

#define NN 50000
#define EE 600000
#define HH 128
#define TAU_INV 2.0f   // 1/TAU, TAU=0.5

typedef __attribute__((ext_vector_type(8))) short short8;
typedef __attribute__((ext_vector_type(4))) float f32x4;

// ---------- helpers ----------
__device__ __forceinline__ float wsum64(float v) {
#pragma unroll
  for (int m = 32; m >= 1; m >>= 1) v += __shfl_xor(v, m, 64);
  return v;
}
__device__ __forceinline__ unsigned short f2bf(float f) {
  unsigned u = __builtin_bit_cast(unsigned, f);
  u = u + 0x7FFFu + ((u >> 16) & 1u);
  return (unsigned short)(u >> 16);
}
__device__ __forceinline__ float bf2f(unsigned short h) {
  unsigned u = ((unsigned)h) << 16;
  return __builtin_bit_cast(float, u);
}

// ---------- CSR build ----------
__global__ void count_k(const int* __restrict__ ei, const int* __restrict__ ea,
                        const int* __restrict__ qp, int* __restrict__ cnt,
                        float* __restrict__ cntq) {
  int e = blockIdx.x * 256 + threadIdx.x;
  if (e >= EE) return;
  int q = *qp;
  int dst = ei[EE + e];
  atomicAdd(&cnt[dst], 1);
  int node = ea[e], he = ea[EE + e];
  atomicAdd(&cnt[NN + he], 1);
  atomicAdd(&cnt[2 * NN + node], 1);
  if (node == q) atomicAdd(&cntq[he], 1.0f);
}

__global__ void derive_k(const int* __restrict__ cnt, float* __restrict__ dinv,
                         float* __restrict__ Binv, float* __restrict__ Dninv) {
  int i = blockIdx.x * 256 + threadIdx.x;
  if (i >= NN) return;
  dinv[i] = rsqrtf((float)(cnt[i] + 1));  // deg includes self-loop
  int b = cnt[NN + i];
  Binv[i] = (b > 0) ? 1.0f / (float)b : 0.0f;
  int d = cnt[2 * NN + i];
  Dninv[i] = (d > 0) ? 1.0f / (float)d : 0.0f;
}

__global__ void scan1(const int* __restrict__ cnt, int* __restrict__ offs,
                      int* __restrict__ aux, int M) {
  __shared__ int s[256];
  int tid = threadIdx.x, gid = blockIdx.x * 256 + tid;
  int v = (gid < M) ? cnt[gid] : 0;
  s[tid] = v;
  __syncthreads();
  for (int d = 1; d < 256; d <<= 1) {
    int t = (tid >= d) ? s[tid - d] : 0;
    __syncthreads();
    s[tid] += t;
    __syncthreads();
  }
  if (gid < M) offs[gid] = s[tid] - v;  // exclusive
  if (tid == 255) aux[blockIdx.x] = s[255];
}

__global__ void scan2(int* __restrict__ aux, int nb) {
  __shared__ int s[1024];
  int tid = threadIdx.x;
  int v = (tid < nb) ? aux[tid] : 0;
  s[tid] = v;
  __syncthreads();
  for (int d = 1; d < 1024; d <<= 1) {
    int t = (tid >= d) ? s[tid - d] : 0;
    __syncthreads();
    s[tid] += t;
    __syncthreads();
  }
  if (tid < nb) aux[tid] = s[tid] - v;
}

__global__ void scan3(int* __restrict__ offs, const int* __restrict__ aux, int M) {
  int gid = blockIdx.x * 256 + threadIdx.x;
  if (gid < M) offs[gid] += aux[blockIdx.x];
}

// fill CSR slots + analytic query coefficients (merged shq)
__global__ void fill_k(const int* __restrict__ ei, const int* __restrict__ ea,
                       const int* __restrict__ qp, const int* __restrict__ offs,
                       int* __restrict__ cursor, int* __restrict__ slots,
                       const float* __restrict__ dinv, const float* __restrict__ Binv,
                       const float* __restrict__ cntq, float* __restrict__ s_hq,
                       float* __restrict__ s_hgq) {
  int e = blockIdx.x * 256 + threadIdx.x;
  if (e >= EE) return;
  int q = *qp;
  int src = ei[e], dst = ei[EE + e];
  int p = offs[dst] + atomicAdd(&cursor[dst], 1);
  slots[p] = src;
  int node = ea[e], he = ea[EE + e];
  int p2 = offs[NN + he] + atomicAdd(&cursor[NN + he], 1);
  slots[p2] = node;
  int p3 = offs[2 * NN + node] + atomicAdd(&cursor[2 * NN + node], 1);
  slots[p3] = he;
  if (src == q) atomicAdd(&s_hq[dst], dinv[q] * dinv[dst]);
  float t = Binv[he] * cntq[he];
  if (t != 0.0f) atomicAdd(&s_hgq[node], t);
}

__global__ void mask_k(const int* __restrict__ pos, const int* __restrict__ qp,
                       int* __restrict__ maskI, float* __restrict__ s_hq,
                       const float* __restrict__ dinv) {
  int t = threadIdx.x;
  if (t < 100) maskI[pos[t]] = 1;
  __syncthreads();
  if (t == 0) {
    int q = *qp;
    maskI[q] = 0;
    s_hq[q] += dinv[q] * dinv[q];  // self-loop contribution of the query gcn
  }
}

// ---------- fp32 -> bf16 convert ----------
__global__ void convert_k(const float4* __restrict__ in, ushort4* __restrict__ out, int n4) {
  int i = blockIdx.x * 256 + threadIdx.x;
  if (i >= n4) return;
  float4 v = in[i];
  ushort4 o;
  o.x = f2bf(v.x); o.y = f2bf(v.y); o.z = f2bf(v.z); o.w = f2bf(v.w);
  out[i] = o;
}

// ---------- pack 7 weight matrices into MFMA B-fragment order ----------
// frag(lane) for (mat,s,c): 8 bf16 = W[32s + (lane>>4)*8 + j][16c + (lane&15)], j=0..7
__global__ void pack_k(const float* __restrict__ W0, const float* __restrict__ Wh0,
                       const float* __restrict__ Wlf, const float* __restrict__ Wf0,
                       const float* __restrict__ Wfh0, const float* __restrict__ Wm1,
                       const float* __restrict__ Wm2, unsigned short* __restrict__ out) {
  int tid = blockIdx.x * 256 + threadIdx.x;
  if (tid >= 7 * 2048) return;
  int mat = tid >> 11, r = tid & 2047;
  int s = r >> 9, c = (r >> 6) & 7, lane = r & 63;
  const float* W = (mat == 0) ? W0 : (mat == 1) ? Wh0 : (mat == 2) ? Wlf
                 : (mat == 3) ? Wf0 : (mat == 4) ? Wfh0 : (mat == 5) ? Wm1 : Wm2;
  int k0 = 32 * s + (lane >> 4) * 8;
  int n = 16 * c + (lane & 15);
  unsigned short* o = out + (size_t)tid * 8;
#pragma unroll
  for (int j = 0; j < 8; ++j) o[j] = f2bf(W[(k0 + j) * 128 + n]);
}

// ---------- MFMA GEMM: out[N,128] = op(A_bf16[N,128] @ W) ----------
#define LDSW 136  // 128 + 8 bf16 pad: lane stride 272B = 68 dwords = 4 mod 32 -> 2-way
template <bool BIAS, bool RELU, bool OUTBF16>
__global__ __launch_bounds__(256) void gemm_mfma(const unsigned short* __restrict__ A,
                                                 const short8* __restrict__ Wp,
                                                 const float* __restrict__ bias,
                                                 void* __restrict__ outv, int nrows) {
  __shared__ unsigned short As[64 * LDSW];
  const int tid = threadIdx.x;
  const int r0 = blockIdx.x * 64;
#pragma unroll
  for (int t = 0; t < 4; ++t) {
    int v = t * 256 + tid;
    int row = v >> 4, cc = v & 15;
    int gr = r0 + row;
    uint4 val = make_uint4(0, 0, 0, 0);
    if (gr < nrows) val = ((const uint4*)A)[(size_t)gr * 16 + cc];
    *(uint4*)&As[row * LDSW + cc * 8] = val;
  }
  __syncthreads();
  const int wave = tid >> 6, lane = tid & 63;
  const int quad = lane >> 4, l15 = lane & 15;
  const int rw = r0 + wave * 16;
  f32x4 acc[8];
#pragma unroll
  for (int c = 0; c < 8; ++c) acc[c] = (f32x4){0.f, 0.f, 0.f, 0.f};
#pragma unroll
  for (int s = 0; s < 4; ++s) {
    short8 a = *(const short8*)&As[(wave * 16 + l15) * LDSW + s * 32 + quad * 8];
#pragma unroll
    for (int c = 0; c < 8; ++c) {
      short8 b = Wp[(s * 8 + c) * 64 + lane];
      acc[c] = __builtin_amdgcn_mfma_f32_16x16x32_bf16(a, b, acc[c], 0, 0, 0);
    }
  }
#pragma unroll
  for (int c = 0; c < 8; ++c) {
    int col = c * 16 + l15;
    float bv = BIAS ? bias[col] : 0.f;
#pragma unroll
    for (int r = 0; r < 4; ++r) {
      int grow = rw + quad * 4 + r;
      if (grow < nrows) {
        float v = acc[c][r] + bv;
        if (RELU) v = fmaxf(v, 0.f);
        if (OUTBF16)
          ((unsigned short*)outv)[(size_t)grow * 128 + col] = f2bf(v);
        else
          ((float*)outv)[(size_t)grow * 128 + col] = v;
      }
    }
  }
}

// 3 GEMMs sharing the A tile: out0 bf16 (no bias), out1 bf16 (no bias), out2 fp32 (+bias2)
__global__ __launch_bounds__(256) void gemm3_mfma(const unsigned short* __restrict__ A,
                                                  const short8* __restrict__ Wp,  // mats 0,1,2
                                                  const float* __restrict__ bias2,
                                                  unsigned short* __restrict__ out0,
                                                  unsigned short* __restrict__ out1,
                                                  float* __restrict__ out2, int nrows) {
  __shared__ unsigned short As[64 * LDSW];
  const int tid = threadIdx.x;
  const int r0 = blockIdx.x * 64;
#pragma unroll
  for (int t = 0; t < 4; ++t) {
    int v = t * 256 + tid;
    int row = v >> 4, cc = v & 15;
    int gr = r0 + row;
    uint4 val = make_uint4(0, 0, 0, 0);
    if (gr < nrows) val = ((const uint4*)A)[(size_t)gr * 16 + cc];
    *(uint4*)&As[row * LDSW + cc * 8] = val;
  }
  __syncthreads();
  const int wave = tid >> 6, lane = tid & 63;
  const int quad = lane >> 4, l15 = lane & 15;
  const int rw = r0 + wave * 16;
  f32x4 acc[3][8];
#pragma unroll
  for (int m = 0; m < 3; ++m)
#pragma unroll
    for (int c = 0; c < 8; ++c) acc[m][c] = (f32x4){0.f, 0.f, 0.f, 0.f};
#pragma unroll
  for (int s = 0; s < 4; ++s) {
    short8 a = *(const short8*)&As[(wave * 16 + l15) * LDSW + s * 32 + quad * 8];
#pragma unroll
    for (int m = 0; m < 3; ++m)
#pragma unroll
      for (int c = 0; c < 8; ++c) {
        short8 b = Wp[(size_t)m * 2048 + (s * 8 + c) * 64 + lane];
        acc[m][c] = __builtin_amdgcn_mfma_f32_16x16x32_bf16(a, b, acc[m][c], 0, 0, 0);
      }
  }
#pragma unroll
  for (int c = 0; c < 8; ++c) {
    int col = c * 16 + l15;
    float bv = bias2[col];
#pragma unroll
    for (int r = 0; r < 4; ++r) {
      int grow = rw + quad * 4 + r;
      if (grow < nrows) {
        out0[(size_t)grow * 128 + col] = f2bf(acc[0][c][r]);
        out1[(size_t)grow * 128 + col] = f2bf(acc[1][c][r]);
        out2[(size_t)grow * 128 + col] = acc[2][c][r] + bv;
      }
    }
  }
}

// ---------- dual gather (CSR), bf16 I/O ----------
// MODE 0: y[i] = wv[i]*(wv[i]*x[i] + sum_s wv[s]*x[s])   (GCN w/ self-loop)
// MODE 1: y[i] = wv[i]*sum_s x[s]                         (hypergraph halves)
template <int MODE>
__global__ void dgather_k(const ushort4* __restrict__ x1, const ushort4* __restrict__ x2,
                          ushort4* __restrict__ y1, ushort4* __restrict__ y2,
                          const int* __restrict__ offs, const int* __restrict__ cnt,
                          const int* __restrict__ slots, const float* __restrict__ wv) {
  int node = blockIdx.x * 8 + (threadIdx.x >> 5);
  if (node >= NN) return;
  int c4 = threadIdx.x & 31;
  int st = offs[node], n = cnt[node];
  float a1x = 0.f, a1y = 0.f, a1z = 0.f, a1w = 0.f;
  float a2x = 0.f, a2y = 0.f, a2z = 0.f, a2w = 0.f;
  for (int p = 0; p < n; ++p) {
    int s = slots[st + p];
    ushort4 v1 = x1[(size_t)s * 32 + c4];
    ushort4 v2 = x2[(size_t)s * 32 + c4];
    if (MODE == 0) {
      float f = wv[s];
      a1x = fmaf(f, bf2f(v1.x), a1x); a1y = fmaf(f, bf2f(v1.y), a1y);
      a1z = fmaf(f, bf2f(v1.z), a1z); a1w = fmaf(f, bf2f(v1.w), a1w);
      a2x = fmaf(f, bf2f(v2.x), a2x); a2y = fmaf(f, bf2f(v2.y), a2y);
      a2z = fmaf(f, bf2f(v2.z), a2z); a2w = fmaf(f, bf2f(v2.w), a2w);
    } else {
      a1x += bf2f(v1.x); a1y += bf2f(v1.y); a1z += bf2f(v1.z); a1w += bf2f(v1.w);
      a2x += bf2f(v2.x); a2y += bf2f(v2.y); a2z += bf2f(v2.z); a2w += bf2f(v2.w);
    }
  }
  float sc = wv[node];
  ushort4 o1, o2;
  if (MODE == 0) {
    ushort4 s1 = x1[(size_t)node * 32 + c4];
    ushort4 s2 = x2[(size_t)node * 32 + c4];
    o1.x = f2bf(sc * fmaf(sc, bf2f(s1.x), a1x)); o1.y = f2bf(sc * fmaf(sc, bf2f(s1.y), a1y));
    o1.z = f2bf(sc * fmaf(sc, bf2f(s1.z), a1z)); o1.w = f2bf(sc * fmaf(sc, bf2f(s1.w), a1w));
    o2.x = f2bf(sc * fmaf(sc, bf2f(s2.x), a2x)); o2.y = f2bf(sc * fmaf(sc, bf2f(s2.y), a2y));
    o2.z = f2bf(sc * fmaf(sc, bf2f(s2.z), a2z)); o2.w = f2bf(sc * fmaf(sc, bf2f(s2.w), a2w));
  } else {
    o1.x = f2bf(sc * a1x); o1.y = f2bf(sc * a1y); o1.z = f2bf(sc * a1z); o1.w = f2bf(sc * a1w);
    o2.x = f2bf(sc * a2x); o2.y = f2bf(sc * a2y); o2.z = f2bf(sc * a2z); o2.w = f2bf(sc * a2w);
  }
  y1[(size_t)node * 32 + c4] = o1;
  y2[(size_t)node * 32 + c4] = o2;
}

// ---------- fused: fuse(analytic-query, conv) + residual + relu -> bf16 ----------
// hq=relu(s*Wq+bq); h=relu(g+bm); fused=softmax2(hq.aq,h.am); out=relu(fused+gr+bres)
__global__ void fuse_add_k(const unsigned short* __restrict__ g,
                           const unsigned short* __restrict__ gr,
                           const float* __restrict__ svec, const float* __restrict__ dscale,
                           const float* __restrict__ Wq, const float* __restrict__ bq,
                           const float* __restrict__ bm, const float* __restrict__ aq,
                           const float* __restrict__ am, const float* __restrict__ bres,
                           unsigned short* __restrict__ out) {
  int row = blockIdx.x * 4 + (threadIdx.x >> 6);
  if (row >= NN) return;
  int lane = threadIdx.x & 63;
  int c0 = lane, c1 = lane + 64;
  float s = svec[row];
  if (dscale) s *= dscale[row];
  float hq0 = fmaxf(fmaf(s, Wq[c0], bq[c0]), 0.f);
  float hq1 = fmaxf(fmaf(s, Wq[c1], bq[c1]), 0.f);
  float h0 = fmaxf(bf2f(g[(size_t)row * 128 + c0]) + bm[c0], 0.f);
  float h1 = fmaxf(bf2f(g[(size_t)row * 128 + c1]) + bm[c1], 0.f);
  float dq = wsum64(hq0 * aq[c0] + hq1 * aq[c1]);
  float dm = wsum64(h0 * am[c0] + h1 * am[c1]);
  float mx = fmaxf(dq, dm);
  float e0 = expf(dq - mx), e1 = expf(dm - mx);
  float w0 = e0 / (e0 + e1), w1 = 1.f - w0;
  float r0 = fmaxf(w0 * hq0 + w1 * h0 + bf2f(gr[(size_t)row * 128 + c0]) + bres[c0], 0.f);
  float r1 = fmaxf(w0 * hq1 + w1 * h1 + bf2f(gr[(size_t)row * 128 + c1]) + bres[c1], 0.f);
  out[(size_t)row * 128 + c0] = f2bf(r0);
  out[(size_t)row * 128 + c1] = f2bf(r1);
}

// ---------- fuse2: hf_ and hfh_ from analytic querys2 and feats2 -> bf16 ----------
__global__ void fuse2_k(const float* __restrict__ f2, const int* __restrict__ qp,
                        const float* __restrict__ Wlq, const float* __restrict__ blq,
                        const float* __restrict__ aq1, const float* __restrict__ a1,
                        const float* __restrict__ aq2, const float* __restrict__ a2,
                        unsigned short* __restrict__ out1, unsigned short* __restrict__ out2) {
  int row = blockIdx.x * 4 + (threadIdx.x >> 6);
  if (row >= NN) return;
  int lane = threadIdx.x & 63;
  int c0 = lane, c1 = lane + 64;
  int q = *qp;
  float q20 = blq[c0] + ((row == q) ? Wlq[c0] : 0.f);
  float q21 = blq[c1] + ((row == q) ? Wlq[c1] : 0.f);
  float f0 = f2[(size_t)row * 128 + c0];
  float f1 = f2[(size_t)row * 128 + c1];
  float dq1 = wsum64(q20 * aq1[c0] + q21 * aq1[c1]);
  float df1 = wsum64(f0 * a1[c0] + f1 * a1[c1]);
  float dq2 = wsum64(q20 * aq2[c0] + q21 * aq2[c1]);
  float df2 = wsum64(f0 * a2[c0] + f1 * a2[c1]);
  {
    float mx = fmaxf(dq1, df1);
    float e0 = expf(dq1 - mx), e1 = expf(df1 - mx);
    float w0 = e0 / (e0 + e1), w1 = 1.f - w0;
    out1[(size_t)row * 128 + c0] = f2bf(w0 * q20 + w1 * f0);
    out1[(size_t)row * 128 + c1] = f2bf(w0 * q21 + w1 * f1);
  }
  {
    float mx = fmaxf(dq2, df2);
    float e0 = expf(dq2 - mx), e1 = expf(df2 - mx);
    float w0 = e0 / (e0 + e1), w1 = 1.f - w0;
    out2[(size_t)row * 128 + c0] = f2bf(w0 * q20 + w1 * f0);
    out2[(size_t)row * 128 + c1] = f2bf(w0 * q21 + w1 * f1);
  }
}

// ---------- q-row norms ----------
__global__ void qnorm_k(const float* __restrict__ z, const float* __restrict__ za,
                        const int* __restrict__ qp, float* __restrict__ scal) {
  int lane = threadIdx.x & 63;
  int q = *qp;
  float zq0 = z[(size_t)q * 128 + lane], zq1 = z[(size_t)q * 128 + lane + 64];
  float zaq0 = za[(size_t)q * 128 + lane], zaq1 = za[(size_t)q * 128 + lane + 64];
  float nq = wsum64(zq0 * zq0 + zq1 * zq1);
  float naq = wsum64(zaq0 * zaq0 + zaq1 * zaq1);
  if (lane == 0) {
    scal[11] = sqrtf(nq);
    scal[12] = sqrtf(naq);
  }
}

// ---------- per-row cosine logits (no atomics) ----------
__global__ void sim_k(const float* __restrict__ z, const float* __restrict__ za,
                      const int* __restrict__ qp, const float* __restrict__ scal,
                      float4* __restrict__ simbuf, float* __restrict__ scal_out) {
  int row = blockIdx.x * 4 + (threadIdx.x >> 6);
  if (row >= NN) return;
  int lane = threadIdx.x & 63;
  int c0 = lane, c1 = lane + 64;
  int q = *qp;
  float zi0 = z[(size_t)row * 128 + c0], zi1 = z[(size_t)row * 128 + c1];
  float zai0 = za[(size_t)row * 128 + c0], zai1 = za[(size_t)row * 128 + c1];
  float zq0 = z[(size_t)q * 128 + c0], zq1 = z[(size_t)q * 128 + c1];
  float zaq0 = za[(size_t)q * 128 + c0], zaq1 = za[(size_t)q * 128 + c1];
  float nzi = wsum64(zi0 * zi0 + zi1 * zi1);
  float nzai = wsum64(zai0 * zai0 + zai1 * zai1);
  float d1 = wsum64(zi0 * zq0 + zi1 * zq1);
  float d2 = wsum64(zai0 * zaq0 + zai1 * zaq1);
  float d3 = wsum64(zai0 * zq0 + zai1 * zq1);
  float d4 = wsum64(zi0 * zaq0 + zi1 * zaq1);
  if (lane == 0) {
    float ni = sqrtf(nzi), nai = sqrtf(nzai);
    float nq = scal[11], naq = scal[12];
    float c1_ = d1 / fmaxf(ni * nq, 1e-8f) * TAU_INV;
    float ca1 = d2 / fmaxf(nai * naq, 1e-8f) * TAU_INV;
    float c2_ = d3 / fmaxf(nai * nq, 1e-8f) * TAU_INV;
    float ca2 = d4 / fmaxf(ni * naq, 1e-8f) * TAU_INV;
    simbuf[row] = make_float4(c1_, ca1, c2_, ca2);
    if (row == q) {
      scal_out[9] = c2_;
      scal_out[10] = ca2;
    }
  }
}

__global__ __launch_bounds__(256) void reduce_sim_k(const float4* __restrict__ simbuf,
                                                    const int* __restrict__ maskI,
                                                    float* __restrict__ scal) {
  float acc[9];
#pragma unroll
  for (int i = 0; i < 9; ++i) acc[i] = 0.f;
  for (int row = blockIdx.x * 256 + threadIdx.x; row < NN; row += gridDim.x * 256) {
    float4 v = simbuf[row];
    acc[0] += expf(v.x);
    acc[1] += expf(v.y);
    acc[2] += expf(v.z);
    acc[3] += expf(v.w);
    if (maskI[row]) {
      acc[4] += v.x; acc[5] += v.y; acc[6] += v.z; acc[7] += v.w;
      acc[8] += 1.0f;
    }
  }
  __shared__ float s[9][4];
  int lane = threadIdx.x & 63, wv = threadIdx.x >> 6;
#pragma unroll
  for (int i = 0; i < 9; ++i) {
    float r = wsum64(acc[i]);
    if (lane == 0) s[i][wv] = r;
  }
  __syncthreads();
  if (threadIdx.x < 9) {
    float r = s[threadIdx.x][0] + s[threadIdx.x][1] + s[threadIdx.x][2] + s[threadIdx.x][3];
    atomicAdd(&scal[threadIdx.x], r);
  }
}

__global__ void final_k(const float* __restrict__ scal, float* __restrict__ out) {
  if (threadIdx.x != 0 || blockIdx.x != 0) return;
  float S1 = scal[0], Sa1 = scal[1], S2 = scal[2], Sa2 = scal[3];
  float L1 = scal[4], La1 = scal[5], L2 = scal[6], La2 = scal[7];
  float NM = scal[8], Q2 = scal[9], Qa2 = scal[10];
  float intra = 0.5f * ((logf(S1) - L1 / NM) + (logf(Sa1) - La1 / NM));
  float inter = 0.5f * ((logf(S2) - L2 / NM) + (logf(Sa2) - La2 / NM));
  float unsup = 0.5f * (logf(S2) - Q2) + 0.5f * (logf(Sa2) - Qa2);
  out[0] = intra + 0.5f * inter + 0.5f * unsup;  // ALPHA=0.5, LAM=0.5
}

// ---------- host ----------
extern "C" void kernel_launch(void* const* d_in, const int* in_sizes, int n_in,
                              void* d_out, int out_size, void* d_ws, size_t ws_size,
                              hipStream_t stream) {
  const float* feats = (const float*)d_in[0];
  const int* ei = (const int*)d_in[1];
  const int* ea = (const int*)d_in[2];
  const int* pos = (const int*)d_in[3];
  const int* qp = (const int*)d_in[4];
  const float* Wq0 = (const float*)d_in[5];
  const float* bq0 = (const float*)d_in[6];
  const float* W0 = (const float*)d_in[7];
  const float* b0 = (const float*)d_in[8];
  const float* Whq0 = (const float*)d_in[9];
  const float* bhq0 = (const float*)d_in[10];
  const float* Wh0 = (const float*)d_in[11];
  const float* bh0 = (const float*)d_in[12];
  const float* Wf0 = (const float*)d_in[13];
  const float* bf0 = (const float*)d_in[14];
  const float* Wfh0 = (const float*)d_in[15];
  const float* bfh0 = (const float*)d_in[16];
  const float* aq0 = (const float*)d_in[17];
  const float* a0 = (const float*)d_in[18];
  const float* ahq0 = (const float*)d_in[19];
  const float* ah0 = (const float*)d_in[20];
  const float* aq_ = (const float*)d_in[21];
  const float* a_ = (const float*)d_in[22];
  const float* ahq_ = (const float*)d_in[23];
  const float* ah_ = (const float*)d_in[24];
  const float* Wlq = (const float*)d_in[25];
  const float* blq = (const float*)d_in[26];
  const float* Wlf = (const float*)d_in[27];
  const float* blf = (const float*)d_in[28];
  const float* Wm1 = (const float*)d_in[29];
  const float* bm1 = (const float*)d_in[30];
  const float* Wm2 = (const float*)d_in[31];
  const float* bm2 = (const float*)d_in[32];

  char* ws = (char*)d_ws;
  size_t off = 0;
  auto take = [&](size_t bytes) -> void* {
    void* p = ws + off;
    off = (off + bytes + 255) & ~(size_t)255;
    return p;
  };
  // ---- zero region ----
  int* cnt3 = (int*)take(3 * NN * 4);
  int* cursor3 = (int*)take(3 * NN * 4);
  int* aux = (int*)take(1024 * 4);
  int* maskI = (int*)take(NN * 4);
  float* s_hq = (float*)take(NN * 4);
  float* cntq = (float*)take(NN * 4);
  float* s_hgq = (float*)take(NN * 4);
  float* scal = (float*)take(64 * 4);
  size_t zero_end = off;
  // ---- non-zeroed scratch ----
  int* offs3 = (int*)take(3 * NN * 4);
  int* slots = (int*)take((size_t)3 * EE * 4);
  float* dinv = (float*)take(NN * 4);
  float* Binv = (float*)take(NN * 4);
  float* Dninv = (float*)take(NN * 4);
  float4* simbuf = (float4*)take((size_t)NN * 16);
  unsigned short* Wpack = (unsigned short*)take((size_t)7 * 16384 * 2);
  const size_t BFSZ = (size_t)NN * HH * 2;
  unsigned short* B0 = (unsigned short*)take(BFSZ);
  unsigned short* B1 = (unsigned short*)take(BFSZ);
  unsigned short* B2 = (unsigned short*)take(BFSZ);
  unsigned short* B3 = (unsigned short*)take(BFSZ);
  unsigned short* B4 = (unsigned short*)take(BFSZ);
  unsigned short* B5 = (unsigned short*)take(BFSZ);
  unsigned short* B6 = (unsigned short*)take(BFSZ);
  float* F0 = (float*)take((size_t)NN * HH * 4);
  float* F1 = (float*)take((size_t)NN * HH * 4);

  const int EB = (EE + 255) / 256;
  const int NB = (NN + 255) / 256;
  const int M3 = 3 * NN;
  const int SB = (M3 + 255) / 256;
  const int GMB = (NN + 63) / 64;    // gemm blocks (64 rows each)
  const int GTB = (NN + 7) / 8;      // gather blocks
  const int RB = (NN + 3) / 4;       // row-wave blocks
  const short8* Wp = (const short8*)Wpack;

  hipMemsetAsync(d_ws, 0, zero_end, stream);
  // CSR build + degree vectors + analytic query coefficients
  count_k<<<EB, 256, 0, stream>>>(ei, ea, qp, cnt3, cntq);
  derive_k<<<NB, 256, 0, stream>>>(cnt3, dinv, Binv, Dninv);
  scan1<<<SB, 256, 0, stream>>>(cnt3, offs3, aux, M3);
  scan2<<<1, 1024, 0, stream>>>(aux, SB);
  scan3<<<SB, 256, 0, stream>>>(offs3, aux, M3);
  fill_k<<<EB, 256, 0, stream>>>(ei, ea, qp, offs3, cursor3, slots, dinv, Binv, cntq,
                                 s_hq, s_hgq);
  mask_k<<<1, 128, 0, stream>>>(pos, qp, maskI, s_hq, dinv);

  // dense prep
  convert_k<<<(NN * 32 + 255) / 256, 256, 0, stream>>>((const float4*)feats, (ushort4*)B0,
                                                       NN * 32);
  pack_k<<<(7 * 2048 + 255) / 256, 256, 0, stream>>>(W0, Wh0, Wlf, Wf0, Wfh0, Wm1, Wm2,
                                                     Wpack);
  // feats @ {W0, Wh0, Wlf}: xw0=B1, xwh=B2, feats2=F0
  gemm3_mfma<<<GMB, 256, 0, stream>>>(B0, Wp, blf, B1, B2, F0, NN);
  // hf_ = B3, hfh_ = B4
  fuse2_k<<<RB, 256, 0, stream>>>(F0, qp, Wlq, blq, aq_, a_, ahq_, ah_, B3, B4);
  // xwf = B5 = hf_ @ Wf0 ; xwfh = B6 = hfh_ @ Wfh0
  gemm_mfma<false, false, true><<<GMB, 256, 0, stream>>>(B3, Wp + (size_t)3 * 2048, nullptr,
                                                         B5, NN);
  gemm_mfma<false, false, true><<<GMB, 256, 0, stream>>>(B4, Wp + (size_t)4 * 2048, nullptr,
                                                         B6, NN);
  // gathers: GCN (xw0,xwf)->(g0=B0, gf=B3); HG he (xwh,xwfh)->(m0=B1->? )
  dgather_k<0><<<GTB, 256, 0, stream>>>((const ushort4*)B1, (const ushort4*)B5, (ushort4*)B0,
                                        (ushort4*)B3, offs3, cnt3, slots, dinv);
  dgather_k<1><<<GTB, 256, 0, stream>>>((const ushort4*)B2, (const ushort4*)B6, (ushort4*)B1,
                                        (ushort4*)B5, offs3 + NN, cnt3 + NN, slots, Binv);
  dgather_k<1><<<GTB, 256, 0, stream>>>((const ushort4*)B1, (const ushort4*)B5, (ushort4*)B2,
                                        (ushort4*)B6, offs3 + 2 * NN, cnt3 + 2 * NN, slots,
                                        Dninv);
  // hf = B1 ; h_augf = B5
  fuse_add_k<<<RB, 256, 0, stream>>>(B0, B3, s_hq, nullptr, Wq0, bq0, b0, aq0, a0, bf0, B1);
  fuse_add_k<<<RB, 256, 0, stream>>>(B2, B6, s_hgq, Dninv, Whq0, bhq0, bh0, ahq0, ah0, bfh0,
                                     B5);
  // MLPs: z = F0, z_aug = F1
  gemm_mfma<true, true, true><<<GMB, 256, 0, stream>>>(B1, Wp + (size_t)5 * 2048, bm1, B0, NN);
  gemm_mfma<true, false, false><<<GMB, 256, 0, stream>>>(B0, Wp + (size_t)6 * 2048, bm2, F0,
                                                         NN);
  gemm_mfma<true, true, true><<<GMB, 256, 0, stream>>>(B5, Wp + (size_t)5 * 2048, bm1, B2, NN);
  gemm_mfma<true, false, false><<<GMB, 256, 0, stream>>>(B2, Wp + (size_t)6 * 2048, bm2, F1,
                                                         NN);
  // loss
  qnorm_k<<<1, 64, 0, stream>>>(F0, F1, qp, scal);
  sim_k<<<RB, 256, 0, stream>>>(F0, F1, qp, scal, simbuf, scal);
  reduce_sim_k<<<64, 256, 0, stream>>>(simbuf, maskI, scal);
  final_k<<<1, 64, 0, stream>>>(scal, (float*)d_out);
}

// Round 4
// 654.827 us; speedup vs baseline: 5.5546x; 1.0144x over previous
//
#include <hip/hip_runtime.h>

#define NN 50000
#define EE 600000
#define HH 128
#define TAU_INV 2.0f   // 1/TAU, TAU=0.5
#define PSZ 6250       // NN / 8 partitions (node range per XCD)

typedef __attribute__((ext_vector_type(8))) short short8;
typedef __attribute__((ext_vector_type(4))) float f32x4;

// ---------- helpers ----------
__device__ __forceinline__ float wsum64(float v) {
#pragma unroll
  for (int m = 32; m >= 1; m >>= 1) v += __shfl_xor(v, m, 64);
  return v;
}
__device__ __forceinline__ unsigned short f2bf(float f) {
  unsigned u = __builtin_bit_cast(unsigned, f);
  u = u + 0x7FFFu + ((u >> 16) & 1u);
  return (unsigned short)(u >> 16);
}
__device__ __forceinline__ float bf2f(unsigned short h) {
  unsigned u = ((unsigned)h) << 16;
  return __builtin_bit_cast(float, u);
}

// ---------- CSR build (XCD-partitioned: p = blockIdx & 7 owns nodes [p*PSZ,(p+1)*PSZ)) ----
__global__ void count_k(const int* __restrict__ ei, const int* __restrict__ ea,
                        const int* __restrict__ qp, int* __restrict__ cnt,
                        float* __restrict__ cntq) {
  const int p = blockIdx.x & 7;
  const int lo = p * PSZ, hi = lo + PSZ;
  const int q = *qp;
  const int stride = (gridDim.x >> 3) * 256;
  for (int e = (blockIdx.x >> 3) * 256 + threadIdx.x; e < EE; e += stride) {
    int dst = ei[EE + e];
    if (dst >= lo && dst < hi) atomicAdd(&cnt[dst], 1);
    int node = ea[e], he = ea[EE + e];
    if (he >= lo && he < hi) {
      atomicAdd(&cnt[NN + he], 1);
      if (node == q) atomicAdd(&cntq[he], 1.0f);
    }
    if (node >= lo && node < hi) atomicAdd(&cnt[2 * NN + node], 1);
  }
}

__global__ void derive_k(const int* __restrict__ cnt, float* __restrict__ dinv,
                         float* __restrict__ Binv, float* __restrict__ Dninv) {
  int i = blockIdx.x * 256 + threadIdx.x;
  if (i >= NN) return;
  dinv[i] = rsqrtf((float)(cnt[i] + 1));  // deg includes self-loop
  int b = cnt[NN + i];
  Binv[i] = (b > 0) ? 1.0f / (float)b : 0.0f;
  int d = cnt[2 * NN + i];
  Dninv[i] = (d > 0) ? 1.0f / (float)d : 0.0f;
}

__global__ void scan1(const int* __restrict__ cnt, int* __restrict__ offs,
                      int* __restrict__ aux, int M) {
  __shared__ int s[256];
  int tid = threadIdx.x, gid = blockIdx.x * 256 + tid;
  int v = (gid < M) ? cnt[gid] : 0;
  s[tid] = v;
  __syncthreads();
  for (int d = 1; d < 256; d <<= 1) {
    int t = (tid >= d) ? s[tid - d] : 0;
    __syncthreads();
    s[tid] += t;
    __syncthreads();
  }
  if (gid < M) offs[gid] = s[tid] - v;  // exclusive
  if (tid == 255) aux[blockIdx.x] = s[255];
}

__global__ void scan2(int* __restrict__ aux, int nb) {
  __shared__ int s[1024];
  int tid = threadIdx.x;
  int v = (tid < nb) ? aux[tid] : 0;
  s[tid] = v;
  __syncthreads();
  for (int d = 1; d < 1024; d <<= 1) {
    int t = (tid >= d) ? s[tid - d] : 0;
    __syncthreads();
    s[tid] += t;
    __syncthreads();
  }
  if (tid < nb) aux[tid] = s[tid] - v;
}

__global__ void scan3(int* __restrict__ offs, const int* __restrict__ aux, int M) {
  int gid = blockIdx.x * 256 + threadIdx.x;
  if (gid < M) offs[gid] += aux[blockIdx.x];
}

// fill CSR slots + analytic query coefficients, XCD-partitioned like count_k
__global__ void fill_k(const int* __restrict__ ei, const int* __restrict__ ea,
                       const int* __restrict__ qp, const int* __restrict__ offs,
                       int* __restrict__ cursor, int* __restrict__ slots,
                       const float* __restrict__ dinv, const float* __restrict__ Binv,
                       const float* __restrict__ cntq, float* __restrict__ s_hq,
                       float* __restrict__ s_hgq) {
  const int p = blockIdx.x & 7;
  const int lo = p * PSZ, hi = lo + PSZ;
  const int q = *qp;
  const int stride = (gridDim.x >> 3) * 256;
  for (int e = (blockIdx.x >> 3) * 256 + threadIdx.x; e < EE; e += stride) {
    int src = ei[e], dst = ei[EE + e];
    if (dst >= lo && dst < hi) {
      int pp = offs[dst] + atomicAdd(&cursor[dst], 1);
      slots[pp] = src;
      if (src == q) atomicAdd(&s_hq[dst], dinv[q] * dinv[dst]);
    }
    int node = ea[e], he = ea[EE + e];
    if (he >= lo && he < hi) {
      int p2 = offs[NN + he] + atomicAdd(&cursor[NN + he], 1);
      slots[p2] = node;
    }
    if (node >= lo && node < hi) {
      int p3 = offs[2 * NN + node] + atomicAdd(&cursor[2 * NN + node], 1);
      slots[p3] = he;
      float t = Binv[he] * cntq[he];
      if (t != 0.0f) atomicAdd(&s_hgq[node], t);
    }
  }
}

__global__ void mask_k(const int* __restrict__ pos, const int* __restrict__ qp,
                       int* __restrict__ maskI, float* __restrict__ s_hq,
                       const float* __restrict__ dinv) {
  int t = threadIdx.x;
  if (t < 100) maskI[pos[t]] = 1;
  __syncthreads();
  if (t == 0) {
    int q = *qp;
    maskI[q] = 0;
    s_hq[q] += dinv[q] * dinv[q];  // self-loop contribution of the query gcn
  }
}

// ---------- pack 7 weight matrices into MFMA B-fragment order ----------
__global__ void pack_k(const float* __restrict__ W0, const float* __restrict__ Wh0,
                       const float* __restrict__ Wlf, const float* __restrict__ Wf0,
                       const float* __restrict__ Wfh0, const float* __restrict__ Wm1,
                       const float* __restrict__ Wm2, unsigned short* __restrict__ out) {
  int tid = blockIdx.x * 256 + threadIdx.x;
  if (tid >= 7 * 2048) return;
  int mat = tid >> 11, r = tid & 2047;
  int s = r >> 9, c = (r >> 6) & 7, lane = r & 63;
  const float* W = (mat == 0) ? W0 : (mat == 1) ? Wh0 : (mat == 2) ? Wlf
                 : (mat == 3) ? Wf0 : (mat == 4) ? Wfh0 : (mat == 5) ? Wm1 : Wm2;
  int k0 = 32 * s + (lane >> 4) * 8;
  int n = 16 * c + (lane & 15);
  unsigned short* o = out + (size_t)tid * 8;
#pragma unroll
  for (int j = 0; j < 8; ++j) o[j] = f2bf(W[(k0 + j) * 128 + n]);
}

#define LDSW 136  // 128 + 8 bf16 pad

// ---------- gemm core (A already staged in LDS as bf16) ----------
template <bool BIAS, bool RELU, bool OUTBF16>
__device__ __forceinline__ void gemm_core(const unsigned short* As, const short8* Wp,
                                          const float* bias, void* outv, int r0, int nrows,
                                          int tid) {
  const int wave = tid >> 6, lane = tid & 63;
  const int quad = lane >> 4, l15 = lane & 15;
  const int rw = r0 + wave * 16;
  f32x4 acc[8];
#pragma unroll
  for (int c = 0; c < 8; ++c) acc[c] = (f32x4){0.f, 0.f, 0.f, 0.f};
#pragma unroll
  for (int s = 0; s < 4; ++s) {
    short8 a = *(const short8*)&As[(wave * 16 + l15) * LDSW + s * 32 + quad * 8];
#pragma unroll
    for (int c = 0; c < 8; ++c) {
      short8 b = Wp[(s * 8 + c) * 64 + lane];
      acc[c] = __builtin_amdgcn_mfma_f32_16x16x32_bf16(a, b, acc[c], 0, 0, 0);
    }
  }
#pragma unroll
  for (int c = 0; c < 8; ++c) {
    int col = c * 16 + l15;
    float bv = BIAS ? bias[col] : 0.f;
#pragma unroll
    for (int r = 0; r < 4; ++r) {
      int grow = rw + quad * 4 + r;
      if (grow < nrows) {
        float v = acc[c][r] + bv;
        if (RELU) v = fmaxf(v, 0.f);
        if (OUTBF16)
          ((unsigned short*)outv)[(size_t)grow * 128 + col] = f2bf(v);
        else
          ((float*)outv)[(size_t)grow * 128 + col] = v;
      }
    }
  }
}

__device__ __forceinline__ void stage_bf16(const unsigned short* A, unsigned short* As,
                                           int r0, int nrows, int tid) {
#pragma unroll
  for (int t = 0; t < 4; ++t) {
    int v = t * 256 + tid;
    int row = v >> 4, cc = v & 15;
    int gr = r0 + row;
    uint4 val = make_uint4(0, 0, 0, 0);
    if (gr < nrows) val = ((const uint4*)A)[(size_t)gr * 16 + cc];
    *(uint4*)&As[row * LDSW + cc * 8] = val;
  }
}

// ---------- batched pair GEMM: two independent A@W ----------
template <bool BIAS, bool RELU, bool OUTBF16>
__global__ __launch_bounds__(256) void gemm2_mfma(const unsigned short* __restrict__ A0,
                                                  const unsigned short* __restrict__ A1,
                                                  const short8* __restrict__ Wp0,
                                                  const short8* __restrict__ Wp1,
                                                  const float* __restrict__ b0,
                                                  const float* __restrict__ b1,
                                                  void* __restrict__ o0, void* __restrict__ o1,
                                                  int nrows, int nblk) {
  __shared__ unsigned short As[64 * LDSW];
  int b = blockIdx.x;
  const unsigned short* A = A0;
  const short8* Wp = Wp0;
  const float* bias = b0;
  void* o = o0;
  if (b >= nblk) {
    b -= nblk; A = A1; Wp = Wp1; bias = b1; o = o1;
  }
  const int r0 = b * 64;
  stage_bf16(A, As, r0, nrows, threadIdx.x);
  __syncthreads();
  gemm_core<BIAS, RELU, OUTBF16>(As, Wp, bias, o, r0, nrows, threadIdx.x);
}

// ---------- 3 GEMMs sharing one fp32-A tile (converted in-kernel) ----------
__global__ __launch_bounds__(256) void gemm3_mfma(const float* __restrict__ A,
                                                  const short8* __restrict__ Wp,  // mats 0,1,2
                                                  const float* __restrict__ bias2,
                                                  unsigned short* __restrict__ out0,
                                                  unsigned short* __restrict__ out1,
                                                  float* __restrict__ out2, int nrows) {
  __shared__ unsigned short As[64 * LDSW];
  const int tid = threadIdx.x;
  const int r0 = blockIdx.x * 64;
#pragma unroll
  for (int t = 0; t < 8; ++t) {
    int v = t * 256 + tid;
    int row = v >> 5, c4 = v & 31;  // float4 chunk
    int gr = r0 + row;
    float4 val = make_float4(0.f, 0.f, 0.f, 0.f);
    if (gr < nrows) val = ((const float4*)A)[(size_t)gr * 32 + c4];
    ushort4 o;
    o.x = f2bf(val.x); o.y = f2bf(val.y); o.z = f2bf(val.z); o.w = f2bf(val.w);
    *(ushort4*)&As[row * LDSW + c4 * 4] = o;
  }
  __syncthreads();
  const int wave = tid >> 6, lane = tid & 63;
  const int quad = lane >> 4, l15 = lane & 15;
  const int rw = r0 + wave * 16;
  f32x4 acc[3][8];
#pragma unroll
  for (int m = 0; m < 3; ++m)
#pragma unroll
    for (int c = 0; c < 8; ++c) acc[m][c] = (f32x4){0.f, 0.f, 0.f, 0.f};
#pragma unroll
  for (int s = 0; s < 4; ++s) {
    short8 a = *(const short8*)&As[(wave * 16 + l15) * LDSW + s * 32 + quad * 8];
#pragma unroll
    for (int m = 0; m < 3; ++m)
#pragma unroll
      for (int c = 0; c < 8; ++c) {
        short8 b = Wp[(size_t)m * 2048 + (s * 8 + c) * 64 + lane];
        acc[m][c] = __builtin_amdgcn_mfma_f32_16x16x32_bf16(a, b, acc[m][c], 0, 0, 0);
      }
  }
#pragma unroll
  for (int c = 0; c < 8; ++c) {
    int col = c * 16 + l15;
    float bv = bias2[col];
#pragma unroll
    for (int r = 0; r < 4; ++r) {
      int grow = rw + quad * 4 + r;
      if (grow < nrows) {
        out0[(size_t)grow * 128 + col] = f2bf(acc[0][c][r]);
        out1[(size_t)grow * 128 + col] = f2bf(acc[1][c][r]);
        out2[(size_t)grow * 128 + col] = acc[2][c][r] + bv;
      }
    }
  }
}

// ---------- dual gather body (CSR), bf16 I/O ----------
template <int MODE>
__device__ __forceinline__ void gather_body(const ushort4* __restrict__ x1,
                                            const ushort4* __restrict__ x2,
                                            ushort4* __restrict__ y1, ushort4* __restrict__ y2,
                                            const int* __restrict__ offs,
                                            const int* __restrict__ cnt,
                                            const int* __restrict__ slots,
                                            const float* __restrict__ wv, int blk) {
  int node = blk * 8 + (threadIdx.x >> 5);
  if (node >= NN) return;
  int c4 = threadIdx.x & 31;
  int st = offs[node], n = cnt[node];
  float a1x = 0.f, a1y = 0.f, a1z = 0.f, a1w = 0.f;
  float a2x = 0.f, a2y = 0.f, a2z = 0.f, a2w = 0.f;
  for (int p = 0; p < n; ++p) {
    int s = slots[st + p];
    ushort4 v1 = x1[(size_t)s * 32 + c4];
    ushort4 v2 = x2[(size_t)s * 32 + c4];
    if (MODE == 0) {
      float f = wv[s];
      a1x = fmaf(f, bf2f(v1.x), a1x); a1y = fmaf(f, bf2f(v1.y), a1y);
      a1z = fmaf(f, bf2f(v1.z), a1z); a1w = fmaf(f, bf2f(v1.w), a1w);
      a2x = fmaf(f, bf2f(v2.x), a2x); a2y = fmaf(f, bf2f(v2.y), a2y);
      a2z = fmaf(f, bf2f(v2.z), a2z); a2w = fmaf(f, bf2f(v2.w), a2w);
    } else {
      a1x += bf2f(v1.x); a1y += bf2f(v1.y); a1z += bf2f(v1.z); a1w += bf2f(v1.w);
      a2x += bf2f(v2.x); a2y += bf2f(v2.y); a2z += bf2f(v2.z); a2w += bf2f(v2.w);
    }
  }
  float sc = wv[node];
  ushort4 o1, o2;
  if (MODE == 0) {
    ushort4 s1 = x1[(size_t)node * 32 + c4];
    ushort4 s2 = x2[(size_t)node * 32 + c4];
    o1.x = f2bf(sc * fmaf(sc, bf2f(s1.x), a1x)); o1.y = f2bf(sc * fmaf(sc, bf2f(s1.y), a1y));
    o1.z = f2bf(sc * fmaf(sc, bf2f(s1.z), a1z)); o1.w = f2bf(sc * fmaf(sc, bf2f(s1.w), a1w));
    o2.x = f2bf(sc * fmaf(sc, bf2f(s2.x), a2x)); o2.y = f2bf(sc * fmaf(sc, bf2f(s2.y), a2y));
    o2.z = f2bf(sc * fmaf(sc, bf2f(s2.z), a2z)); o2.w = f2bf(sc * fmaf(sc, bf2f(s2.w), a2w));
  } else {
    o1.x = f2bf(sc * a1x); o1.y = f2bf(sc * a1y); o1.z = f2bf(sc * a1z); o1.w = f2bf(sc * a1w);
    o2.x = f2bf(sc * a2x); o2.y = f2bf(sc * a2y); o2.z = f2bf(sc * a2z); o2.w = f2bf(sc * a2w);
  }
  y1[(size_t)node * 32 + c4] = o1;
  y2[(size_t)node * 32 + c4] = o2;
}

// merged: pass1 (GCN, MODE0, CSR1) + pass2 (HG-he, MODE1, CSR2) — independent
__global__ void dgather12_k(const ushort4* __restrict__ xa1, const ushort4* __restrict__ xa2,
                            ushort4* __restrict__ ya1, ushort4* __restrict__ ya2,
                            const ushort4* __restrict__ xb1, const ushort4* __restrict__ xb2,
                            ushort4* __restrict__ yb1, ushort4* __restrict__ yb2,
                            const int* __restrict__ offs, const int* __restrict__ cnt,
                            const int* __restrict__ slots, const float* __restrict__ wva,
                            const float* __restrict__ wvb, int nblk) {
  int b = blockIdx.x;
  if (b < nblk)
    gather_body<0>(xa1, xa2, ya1, ya2, offs, cnt, slots, wva, b);
  else
    gather_body<1>(xb1, xb2, yb1, yb2, offs + NN, cnt + NN, slots, wvb, b - nblk);
}

template <int MODE>
__global__ void dgather_k(const ushort4* __restrict__ x1, const ushort4* __restrict__ x2,
                          ushort4* __restrict__ y1, ushort4* __restrict__ y2,
                          const int* __restrict__ offs, const int* __restrict__ cnt,
                          const int* __restrict__ slots, const float* __restrict__ wv) {
  gather_body<MODE>(x1, x2, y1, y2, offs, cnt, slots, wv, blockIdx.x);
}

// ---------- fused: fuse(analytic-query, conv) + residual + relu -> bf16 (batched x2) ----------
__device__ __forceinline__ void fuse_add_body(const unsigned short* __restrict__ g,
                                              const unsigned short* __restrict__ gr,
                                              const float* __restrict__ svec,
                                              const float* __restrict__ dscale,
                                              const float* __restrict__ Wq,
                                              const float* __restrict__ bq,
                                              const float* __restrict__ bm,
                                              const float* __restrict__ aq,
                                              const float* __restrict__ am,
                                              const float* __restrict__ bres,
                                              unsigned short* __restrict__ out, int blk) {
  int row = blk * 4 + (threadIdx.x >> 6);
  if (row >= NN) return;
  int lane = threadIdx.x & 63;
  int c0 = lane, c1 = lane + 64;
  float s = svec[row];
  if (dscale) s *= dscale[row];
  float hq0 = fmaxf(fmaf(s, Wq[c0], bq[c0]), 0.f);
  float hq1 = fmaxf(fmaf(s, Wq[c1], bq[c1]), 0.f);
  float h0 = fmaxf(bf2f(g[(size_t)row * 128 + c0]) + bm[c0], 0.f);
  float h1 = fmaxf(bf2f(g[(size_t)row * 128 + c1]) + bm[c1], 0.f);
  float dq = wsum64(hq0 * aq[c0] + hq1 * aq[c1]);
  float dm = wsum64(h0 * am[c0] + h1 * am[c1]);
  float mx = fmaxf(dq, dm);
  float e0 = expf(dq - mx), e1 = expf(dm - mx);
  float w0 = e0 / (e0 + e1), w1 = 1.f - w0;
  float r0 = fmaxf(w0 * hq0 + w1 * h0 + bf2f(gr[(size_t)row * 128 + c0]) + bres[c0], 0.f);
  float r1 = fmaxf(w0 * hq1 + w1 * h1 + bf2f(gr[(size_t)row * 128 + c1]) + bres[c1], 0.f);
  out[(size_t)row * 128 + c0] = f2bf(r0);
  out[(size_t)row * 128 + c1] = f2bf(r1);
}

__global__ void fuse_add2_k(const unsigned short* gA, const unsigned short* grA,
                            const float* svA, const float* dsA, const float* WqA,
                            const float* bqA, const float* bmA, const float* aqA,
                            const float* amA, const float* brA, unsigned short* outA,
                            const unsigned short* gB, const unsigned short* grB,
                            const float* svB, const float* dsB, const float* WqB,
                            const float* bqB, const float* bmB, const float* aqB,
                            const float* amB, const float* brB, unsigned short* outB,
                            int nblk) {
  int b = blockIdx.x;
  if (b < nblk)
    fuse_add_body(gA, grA, svA, dsA, WqA, bqA, bmA, aqA, amA, brA, outA, b);
  else
    fuse_add_body(gB, grB, svB, dsB, WqB, bqB, bmB, aqB, amB, brB, outB, b - nblk);
}

// ---------- fuse2: hf_ and hfh_ from analytic querys2 and feats2 -> bf16 ----------
__global__ void fuse2_k(const float* __restrict__ f2, const int* __restrict__ qp,
                        const float* __restrict__ Wlq, const float* __restrict__ blq,
                        const float* __restrict__ aq1, const float* __restrict__ a1,
                        const float* __restrict__ aq2, const float* __restrict__ a2,
                        unsigned short* __restrict__ out1, unsigned short* __restrict__ out2) {
  int row = blockIdx.x * 4 + (threadIdx.x >> 6);
  if (row >= NN) return;
  int lane = threadIdx.x & 63;
  int c0 = lane, c1 = lane + 64;
  int q = *qp;
  float q20 = blq[c0] + ((row == q) ? Wlq[c0] : 0.f);
  float q21 = blq[c1] + ((row == q) ? Wlq[c1] : 0.f);
  float f0 = f2[(size_t)row * 128 + c0];
  float f1 = f2[(size_t)row * 128 + c1];
  float dq1 = wsum64(q20 * aq1[c0] + q21 * aq1[c1]);
  float df1 = wsum64(f0 * a1[c0] + f1 * a1[c1]);
  float dq2 = wsum64(q20 * aq2[c0] + q21 * aq2[c1]);
  float df2 = wsum64(f0 * a2[c0] + f1 * a2[c1]);
  {
    float mx = fmaxf(dq1, df1);
    float e0 = expf(dq1 - mx), e1 = expf(df1 - mx);
    float w0 = e0 / (e0 + e1), w1 = 1.f - w0;
    out1[(size_t)row * 128 + c0] = f2bf(w0 * q20 + w1 * f0);
    out1[(size_t)row * 128 + c1] = f2bf(w0 * q21 + w1 * f1);
  }
  {
    float mx = fmaxf(dq2, df2);
    float e0 = expf(dq2 - mx), e1 = expf(df2 - mx);
    float w0 = e0 / (e0 + e1), w1 = 1.f - w0;
    out2[(size_t)row * 128 + c0] = f2bf(w0 * q20 + w1 * f0);
    out2[(size_t)row * 128 + c1] = f2bf(w0 * q21 + w1 * f1);
  }
}

// ---------- q-row norms ----------
__global__ void qnorm_k(const float* __restrict__ z, const float* __restrict__ za,
                        const int* __restrict__ qp, float* __restrict__ scal) {
  int lane = threadIdx.x & 63;
  int q = *qp;
  float zq0 = z[(size_t)q * 128 + lane], zq1 = z[(size_t)q * 128 + lane + 64];
  float zaq0 = za[(size_t)q * 128 + lane], zaq1 = za[(size_t)q * 128 + lane + 64];
  float nq = wsum64(zq0 * zq0 + zq1 * zq1);
  float naq = wsum64(zaq0 * zaq0 + zaq1 * zaq1);
  if (lane == 0) {
    scal[11] = sqrtf(nq);
    scal[12] = sqrtf(naq);
  }
}

// ---------- per-row cosine logits (no atomics) ----------
__global__ void sim_k(const float* __restrict__ z, const float* __restrict__ za,
                      const int* __restrict__ qp, const float* __restrict__ scal,
                      float4* __restrict__ simbuf, float* __restrict__ scal_out) {
  int row = blockIdx.x * 4 + (threadIdx.x >> 6);
  if (row >= NN) return;
  int lane = threadIdx.x & 63;
  int c0 = lane, c1 = lane + 64;
  int q = *qp;
  float zi0 = z[(size_t)row * 128 + c0], zi1 = z[(size_t)row * 128 + c1];
  float zai0 = za[(size_t)row * 128 + c0], zai1 = za[(size_t)row * 128 + c1];
  float zq0 = z[(size_t)q * 128 + c0], zq1 = z[(size_t)q * 128 + c1];
  float zaq0 = za[(size_t)q * 128 + c0], zaq1 = za[(size_t)q * 128 + c1];
  float nzi = wsum64(zi0 * zi0 + zi1 * zi1);
  float nzai = wsum64(zai0 * zai0 + zai1 * zai1);
  float d1 = wsum64(zi0 * zq0 + zi1 * zq1);
  float d2 = wsum64(zai0 * zaq0 + zai1 * zaq1);
  float d3 = wsum64(zai0 * zq0 + zai1 * zq1);
  float d4 = wsum64(zi0 * zaq0 + zi1 * zaq1);
  if (lane == 0) {
    float ni = sqrtf(nzi), nai = sqrtf(nzai);
    float nq = scal[11], naq = scal[12];
    float c1_ = d1 / fmaxf(ni * nq, 1e-8f) * TAU_INV;
    float ca1 = d2 / fmaxf(nai * naq, 1e-8f) * TAU_INV;
    float c2_ = d3 / fmaxf(nai * nq, 1e-8f) * TAU_INV;
    float ca2 = d4 / fmaxf(ni * naq, 1e-8f) * TAU_INV;
    simbuf[row] = make_float4(c1_, ca1, c2_, ca2);
    if (row == q) {
      scal_out[9] = c2_;
      scal_out[10] = ca2;
    }
  }
}

__global__ __launch_bounds__(256) void reduce_sim_k(const float4* __restrict__ simbuf,
                                                    const int* __restrict__ maskI,
                                                    float* __restrict__ scal) {
  float acc[9];
#pragma unroll
  for (int i = 0; i < 9; ++i) acc[i] = 0.f;
  for (int row = blockIdx.x * 256 + threadIdx.x; row < NN; row += gridDim.x * 256) {
    float4 v = simbuf[row];
    acc[0] += expf(v.x);
    acc[1] += expf(v.y);
    acc[2] += expf(v.z);
    acc[3] += expf(v.w);
    if (maskI[row]) {
      acc[4] += v.x; acc[5] += v.y; acc[6] += v.z; acc[7] += v.w;
      acc[8] += 1.0f;
    }
  }
  __shared__ float s[9][4];
  int lane = threadIdx.x & 63, wv = threadIdx.x >> 6;
#pragma unroll
  for (int i = 0; i < 9; ++i) {
    float r = wsum64(acc[i]);
    if (lane == 0) s[i][wv] = r;
  }
  __syncthreads();
  if (threadIdx.x < 9) {
    float r = s[threadIdx.x][0] + s[threadIdx.x][1] + s[threadIdx.x][2] + s[threadIdx.x][3];
    atomicAdd(&scal[threadIdx.x], r);
  }
}

__global__ void final_k(const float* __restrict__ scal, float* __restrict__ out) {
  if (threadIdx.x != 0 || blockIdx.x != 0) return;
  float S1 = scal[0], Sa1 = scal[1], S2 = scal[2], Sa2 = scal[3];
  float L1 = scal[4], La1 = scal[5], L2 = scal[6], La2 = scal[7];
  float NM = scal[8], Q2 = scal[9], Qa2 = scal[10];
  float intra = 0.5f * ((logf(S1) - L1 / NM) + (logf(Sa1) - La1 / NM));
  float inter = 0.5f * ((logf(S2) - L2 / NM) + (logf(Sa2) - La2 / NM));
  float unsup = 0.5f * (logf(S2) - Q2) + 0.5f * (logf(Sa2) - Qa2);
  out[0] = intra + 0.5f * inter + 0.5f * unsup;  // ALPHA=0.5, LAM=0.5
}

// ---------- host ----------
extern "C" void kernel_launch(void* const* d_in, const int* in_sizes, int n_in,
                              void* d_out, int out_size, void* d_ws, size_t ws_size,
                              hipStream_t stream) {
  const float* feats = (const float*)d_in[0];
  const int* ei = (const int*)d_in[1];
  const int* ea = (const int*)d_in[2];
  const int* pos = (const int*)d_in[3];
  const int* qp = (const int*)d_in[4];
  const float* Wq0 = (const float*)d_in[5];
  const float* bq0 = (const float*)d_in[6];
  const float* W0 = (const float*)d_in[7];
  const float* b0 = (const float*)d_in[8];
  const float* Whq0 = (const float*)d_in[9];
  const float* bhq0 = (const float*)d_in[10];
  const float* Wh0 = (const float*)d_in[11];
  const float* bh0 = (const float*)d_in[12];
  const float* Wf0 = (const float*)d_in[13];
  const float* bf0 = (const float*)d_in[14];
  const float* Wfh0 = (const float*)d_in[15];
  const float* bfh0 = (const float*)d_in[16];
  const float* aq0 = (const float*)d_in[17];
  const float* a0 = (const float*)d_in[18];
  const float* ahq0 = (const float*)d_in[19];
  const float* ah0 = (const float*)d_in[20];
  const float* aq_ = (const float*)d_in[21];
  const float* a_ = (const float*)d_in[22];
  const float* ahq_ = (const float*)d_in[23];
  const float* ah_ = (const float*)d_in[24];
  const float* Wlq = (const float*)d_in[25];
  const float* blq = (const float*)d_in[26];
  const float* Wlf = (const float*)d_in[27];
  const float* blf = (const float*)d_in[28];
  const float* Wm1 = (const float*)d_in[29];
  const float* bm1 = (const float*)d_in[30];
  const float* Wm2 = (const float*)d_in[31];
  const float* bm2 = (const float*)d_in[32];

  char* ws = (char*)d_ws;
  size_t off = 0;
  auto take = [&](size_t bytes) -> void* {
    void* p = ws + off;
    off = (off + bytes + 255) & ~(size_t)255;
    return p;
  };
  // ---- zero region ----
  int* cnt3 = (int*)take(3 * NN * 4);
  int* cursor3 = (int*)take(3 * NN * 4);
  int* aux = (int*)take(1024 * 4);
  int* maskI = (int*)take(NN * 4);
  float* s_hq = (float*)take(NN * 4);
  float* cntq = (float*)take(NN * 4);
  float* s_hgq = (float*)take(NN * 4);
  float* scal = (float*)take(64 * 4);
  size_t zero_end = off;
  // ---- non-zeroed scratch ----
  int* offs3 = (int*)take(3 * NN * 4);
  int* slots = (int*)take((size_t)3 * EE * 4);
  float* dinv = (float*)take(NN * 4);
  float* Binv = (float*)take(NN * 4);
  float* Dninv = (float*)take(NN * 4);
  float4* simbuf = (float4*)take((size_t)NN * 16);
  unsigned short* Wpack = (unsigned short*)take((size_t)7 * 16384 * 2);
  const size_t BFSZ = (size_t)NN * HH * 2;
  unsigned short* B0 = (unsigned short*)take(BFSZ);
  unsigned short* B1 = (unsigned short*)take(BFSZ);
  unsigned short* B2 = (unsigned short*)take(BFSZ);
  unsigned short* B3 = (unsigned short*)take(BFSZ);
  unsigned short* B4 = (unsigned short*)take(BFSZ);
  unsigned short* B5 = (unsigned short*)take(BFSZ);
  unsigned short* B6 = (unsigned short*)take(BFSZ);
  float* F0 = (float*)take((size_t)NN * HH * 4);
  float* F1 = (float*)take((size_t)NN * HH * 4);
  // bf16 scratch for HG intermediate, carved from F0 (dead between fuse2 and MLP-L2)
  unsigned short* U0 = (unsigned short*)F0;
  unsigned short* U1 = (unsigned short*)F0 + (size_t)NN * HH;

  const int NB = (NN + 255) / 256;
  const int M3 = 3 * NN;
  const int SB = (M3 + 255) / 256;
  const int GMB = (NN + 63) / 64;    // gemm blocks (64 rows each)
  const int GTB = (NN + 7) / 8;      // gather blocks
  const int RB = (NN + 3) / 4;       // row-wave blocks
  const short8* Wp = (const short8*)Wpack;

  hipMemsetAsync(d_ws, 0, zero_end, stream);
  // CSR build (XCD-partitioned) + degree vectors + analytic query coefficients
  count_k<<<512, 256, 0, stream>>>(ei, ea, qp, cnt3, cntq);
  derive_k<<<NB, 256, 0, stream>>>(cnt3, dinv, Binv, Dninv);
  scan1<<<SB, 256, 0, stream>>>(cnt3, offs3, aux, M3);
  scan2<<<1, 1024, 0, stream>>>(aux, SB);
  scan3<<<SB, 256, 0, stream>>>(offs3, aux, M3);
  fill_k<<<512, 256, 0, stream>>>(ei, ea, qp, offs3, cursor3, slots, dinv, Binv, cntq,
                                  s_hq, s_hgq);
  mask_k<<<1, 128, 0, stream>>>(pos, qp, maskI, s_hq, dinv);

  // dense prep
  pack_k<<<(7 * 2048 + 255) / 256, 256, 0, stream>>>(W0, Wh0, Wlf, Wf0, Wfh0, Wm1, Wm2,
                                                     Wpack);
  // feats @ {W0, Wh0, Wlf}: xw0=B1, xwh=B2, feats2=F0 (fp32 staged+converted in-kernel)
  gemm3_mfma<<<GMB, 256, 0, stream>>>(feats, Wp, blf, B1, B2, F0, NN);
  // hf_ = B3, hfh_ = B4
  fuse2_k<<<RB, 256, 0, stream>>>(F0, qp, Wlq, blq, aq_, a_, ahq_, ah_, B3, B4);
  // xwf = B5 = hf_ @ Wf0 ; xwfh = B6 = hfh_ @ Wfh0  (batched)
  gemm2_mfma<false, false, true><<<2 * GMB, 256, 0, stream>>>(
      B3, B4, Wp + (size_t)3 * 2048, Wp + (size_t)4 * 2048, nullptr, nullptr, B5, B6, NN, GMB);
  // gathers: pass1 GCN (B1,B5)->(B0,B3) ; pass2 HG-he (B2,B6)->(U0,U1)  [merged]
  dgather12_k<<<2 * GTB, 256, 0, stream>>>(
      (const ushort4*)B1, (const ushort4*)B5, (ushort4*)B0, (ushort4*)B3,
      (const ushort4*)B2, (const ushort4*)B6, (ushort4*)U0, (ushort4*)U1,
      offs3, cnt3, slots, dinv, Binv, GTB);
  // pass3 HG-node (U0,U1)->(B2,B6)
  dgather_k<1><<<GTB, 256, 0, stream>>>((const ushort4*)U0, (const ushort4*)U1, (ushort4*)B2,
                                        (ushort4*)B6, offs3 + 2 * NN, cnt3 + 2 * NN, slots,
                                        Dninv);
  // hf = B1 ; h_augf = B5  (batched fuse+residual+relu)
  fuse_add2_k<<<2 * RB, 256, 0, stream>>>(
      B0, B3, s_hq, nullptr, Wq0, bq0, b0, aq0, a0, bf0, B1,
      B2, B6, s_hgq, Dninv, Whq0, bhq0, bh0, ahq0, ah0, bfh0, B5, RB);
  // MLPs (batched per layer): L1: (B1->B0),(B5->B2) ; L2: (B0->F0),(B2->F1)
  gemm2_mfma<true, true, true><<<2 * GMB, 256, 0, stream>>>(
      B1, B5, Wp + (size_t)5 * 2048, Wp + (size_t)5 * 2048, bm1, bm1, B0, B2, NN, GMB);
  gemm2_mfma<true, false, false><<<2 * GMB, 256, 0, stream>>>(
      B0, B2, Wp + (size_t)6 * 2048, Wp + (size_t)6 * 2048, bm2, bm2, F0, F1, NN, GMB);
  // loss
  qnorm_k<<<1, 64, 0, stream>>>(F0, F1, qp, scal);
  sim_k<<<RB, 256, 0, stream>>>(F0, F1, qp, scal, simbuf, scal);
  reduce_sim_k<<<64, 256, 0, stream>>>(simbuf, maskI, scal);
  final_k<<<1, 64, 0, stream>>>(scal, (float*)d_out);
}

// Round 5
// 628.000 us; speedup vs baseline: 5.7919x; 1.0427x over previous
//
#include <hip/hip_runtime.h>

#define NN 50000
#define EE 600000
#define HH 128
#define TAU_INV 2.0f   // 1/TAU, TAU=0.5
#define PSZ 6250       // NN / 8 partitions (node range per XCD)

typedef __attribute__((ext_vector_type(8))) short short8;
typedef __attribute__((ext_vector_type(4))) float f32x4;
typedef __attribute__((ext_vector_type(2))) float floatx2;

// ---------- helpers ----------
__device__ __forceinline__ float wsum64(float v) {
#pragma unroll
  for (int m = 32; m >= 1; m >>= 1) v += __shfl_xor(v, m, 64);
  return v;
}
__device__ __forceinline__ unsigned short f2bf(float f) {
  unsigned u = __builtin_bit_cast(unsigned, f);
  u = u + 0x7FFFu + ((u >> 16) & 1u);
  return (unsigned short)(u >> 16);
}
__device__ __forceinline__ float bf2f(unsigned short h) {
  unsigned u = ((unsigned)h) << 16;
  return __builtin_bit_cast(float, u);
}
// fp8 e4m3 (OCP) via gfx950 HW converts
__device__ __forceinline__ unsigned char fp8_enc1(float v) {
  int p = __builtin_amdgcn_cvt_pk_fp8_f32(v, v, 0, false);
  return (unsigned char)(p & 0xFF);
}
__device__ __forceinline__ void fp8x8_dec(uint2 v, float* f) {
  floatx2 a = __builtin_amdgcn_cvt_pk_f32_fp8(v.x, false);
  floatx2 b = __builtin_amdgcn_cvt_pk_f32_fp8(v.x, true);
  floatx2 c = __builtin_amdgcn_cvt_pk_f32_fp8(v.y, false);
  floatx2 d = __builtin_amdgcn_cvt_pk_f32_fp8(v.y, true);
  f[0] = a.x; f[1] = a.y; f[2] = b.x; f[3] = b.y;
  f[4] = c.x; f[5] = c.y; f[6] = d.x; f[7] = d.y;
}
__device__ __forceinline__ uint2 fp8x8_enc(const float* f) {
  int w0 = __builtin_amdgcn_cvt_pk_fp8_f32(f[0], f[1], 0, false);
  w0 = __builtin_amdgcn_cvt_pk_fp8_f32(f[2], f[3], w0, true);
  int w1 = __builtin_amdgcn_cvt_pk_fp8_f32(f[4], f[5], 0, false);
  w1 = __builtin_amdgcn_cvt_pk_fp8_f32(f[6], f[7], w1, true);
  return make_uint2((unsigned)w0, (unsigned)w1);
}

// ---------- CSR build (XCD-partitioned: p = blockIdx & 7 owns nodes [p*PSZ,(p+1)*PSZ)) ----
__global__ void count_k(const int* __restrict__ ei, const int* __restrict__ ea,
                        const int* __restrict__ qp, int* __restrict__ cnt,
                        float* __restrict__ cntq) {
  const int p = blockIdx.x & 7;
  const int lo = p * PSZ, hi = lo + PSZ;
  const int q = *qp;
  const int stride = (gridDim.x >> 3) * 256;
  for (int e = (blockIdx.x >> 3) * 256 + threadIdx.x; e < EE; e += stride) {
    int dst = ei[EE + e];
    if (dst >= lo && dst < hi) atomicAdd(&cnt[dst], 1);
    int node = ea[e], he = ea[EE + e];
    if (he >= lo && he < hi) {
      atomicAdd(&cnt[NN + he], 1);
      if (node == q) atomicAdd(&cntq[he], 1.0f);
    }
    if (node >= lo && node < hi) atomicAdd(&cnt[2 * NN + node], 1);
  }
}

__global__ void derive_k(const int* __restrict__ cnt, float* __restrict__ dinv,
                         float* __restrict__ Binv, float* __restrict__ Dninv) {
  int i = blockIdx.x * 256 + threadIdx.x;
  if (i >= NN) return;
  dinv[i] = rsqrtf((float)(cnt[i] + 1));  // deg includes self-loop
  int b = cnt[NN + i];
  Binv[i] = (b > 0) ? 1.0f / (float)b : 0.0f;
  int d = cnt[2 * NN + i];
  Dninv[i] = (d > 0) ? 1.0f / (float)d : 0.0f;
}

__global__ void scan1(const int* __restrict__ cnt, int* __restrict__ offs,
                      int* __restrict__ aux, int M) {
  __shared__ int s[256];
  int tid = threadIdx.x, gid = blockIdx.x * 256 + tid;
  int v = (gid < M) ? cnt[gid] : 0;
  s[tid] = v;
  __syncthreads();
  for (int d = 1; d < 256; d <<= 1) {
    int t = (tid >= d) ? s[tid - d] : 0;
    __syncthreads();
    s[tid] += t;
    __syncthreads();
  }
  if (gid < M) offs[gid] = s[tid] - v;  // exclusive
  if (tid == 255) aux[blockIdx.x] = s[255];
}

__global__ void scan2(int* __restrict__ aux, int nb) {
  __shared__ int s[1024];
  int tid = threadIdx.x;
  int v = (tid < nb) ? aux[tid] : 0;
  s[tid] = v;
  __syncthreads();
  for (int d = 1; d < 1024; d <<= 1) {
    int t = (tid >= d) ? s[tid - d] : 0;
    __syncthreads();
    s[tid] += t;
    __syncthreads();
  }
  if (tid < nb) aux[tid] = s[tid] - v;
}

__global__ void scan3(int* __restrict__ offs, const int* __restrict__ aux, int M) {
  int gid = blockIdx.x * 256 + threadIdx.x;
  if (gid < M) offs[gid] += aux[blockIdx.x];
}

// fill CSR slots + analytic query coefficients, XCD-partitioned
__global__ void fill_k(const int* __restrict__ ei, const int* __restrict__ ea,
                       const int* __restrict__ qp, const int* __restrict__ offs,
                       int* __restrict__ cursor, int* __restrict__ slots,
                       const float* __restrict__ dinv, const float* __restrict__ Binv,
                       const float* __restrict__ cntq, float* __restrict__ s_hq,
                       float* __restrict__ s_hgq) {
  const int p = blockIdx.x & 7;
  const int lo = p * PSZ, hi = lo + PSZ;
  const int q = *qp;
  const int stride = (gridDim.x >> 3) * 256;
  for (int e = (blockIdx.x >> 3) * 256 + threadIdx.x; e < EE; e += stride) {
    int src = ei[e], dst = ei[EE + e];
    if (dst >= lo && dst < hi) {
      int pp = offs[dst] + atomicAdd(&cursor[dst], 1);
      slots[pp] = src;
      if (src == q) atomicAdd(&s_hq[dst], dinv[q] * dinv[dst]);
    }
    int node = ea[e], he = ea[EE + e];
    if (he >= lo && he < hi) {
      int p2 = offs[NN + he] + atomicAdd(&cursor[NN + he], 1);
      slots[p2] = node;
    }
    if (node >= lo && node < hi) {
      int p3 = offs[2 * NN + node] + atomicAdd(&cursor[2 * NN + node], 1);
      slots[p3] = he;
      float t = Binv[he] * cntq[he];
      if (t != 0.0f) atomicAdd(&s_hgq[node], t);
    }
  }
}

__global__ void mask_k(const int* __restrict__ pos, const int* __restrict__ qp,
                       int* __restrict__ maskI, float* __restrict__ s_hq,
                       const float* __restrict__ dinv) {
  int t = threadIdx.x;
  if (t < 100) maskI[pos[t]] = 1;
  __syncthreads();
  if (t == 0) {
    int q = *qp;
    maskI[q] = 0;
    s_hq[q] += dinv[q] * dinv[q];  // self-loop contribution of the query gcn
  }
}

// ---------- pack 7 weight matrices into MFMA B-fragment order ----------
__global__ void pack_k(const float* __restrict__ W0, const float* __restrict__ Wh0,
                       const float* __restrict__ Wlf, const float* __restrict__ Wf0,
                       const float* __restrict__ Wfh0, const float* __restrict__ Wm1,
                       const float* __restrict__ Wm2, unsigned short* __restrict__ out) {
  int tid = blockIdx.x * 256 + threadIdx.x;
  if (tid >= 7 * 2048) return;
  int mat = tid >> 11, r = tid & 2047;
  int s = r >> 9, c = (r >> 6) & 7, lane = r & 63;
  const float* W = (mat == 0) ? W0 : (mat == 1) ? Wh0 : (mat == 2) ? Wlf
                 : (mat == 3) ? Wf0 : (mat == 4) ? Wfh0 : (mat == 5) ? Wm1 : Wm2;
  int k0 = 32 * s + (lane >> 4) * 8;
  int n = 16 * c + (lane & 15);
  unsigned short* o = out + (size_t)tid * 8;
#pragma unroll
  for (int j = 0; j < 8; ++j) o[j] = f2bf(W[(k0 + j) * 128 + n]);
}

#define LDSW 136  // 128 + 8 bf16 pad

// ---------- gemm core (A already staged in LDS as bf16) ----------
// OM: 0 = fp32 out (stride 128 f32), 1 = bf16 out (stride 128), 2 = fp8 out (uchar*, stride 256)
template <bool BIAS, bool RELU, int OM>
__device__ __forceinline__ void gemm_core(const unsigned short* As, const short8* Wp,
                                          const float* bias, void* outv, int r0, int nrows,
                                          int tid) {
  const int wave = tid >> 6, lane = tid & 63;
  const int quad = lane >> 4, l15 = lane & 15;
  const int rw = r0 + wave * 16;
  f32x4 acc[8];
#pragma unroll
  for (int c = 0; c < 8; ++c) acc[c] = (f32x4){0.f, 0.f, 0.f, 0.f};
#pragma unroll
  for (int s = 0; s < 4; ++s) {
    short8 a = *(const short8*)&As[(wave * 16 + l15) * LDSW + s * 32 + quad * 8];
#pragma unroll
    for (int c = 0; c < 8; ++c) {
      short8 b = Wp[(s * 8 + c) * 64 + lane];
      acc[c] = __builtin_amdgcn_mfma_f32_16x16x32_bf16(a, b, acc[c], 0, 0, 0);
    }
  }
#pragma unroll
  for (int c = 0; c < 8; ++c) {
    int col = c * 16 + l15;
    float bv = BIAS ? bias[col] : 0.f;
#pragma unroll
    for (int r = 0; r < 4; ++r) {
      int grow = rw + quad * 4 + r;
      if (grow < nrows) {
        float v = acc[c][r] + bv;
        if (RELU) v = fmaxf(v, 0.f);
        if (OM == 2)
          ((unsigned char*)outv)[(size_t)grow * 256 + col] = fp8_enc1(v);
        else if (OM == 1)
          ((unsigned short*)outv)[(size_t)grow * 128 + col] = f2bf(v);
        else
          ((float*)outv)[(size_t)grow * 128 + col] = v;
      }
    }
  }
}

__device__ __forceinline__ void stage_bf16(const unsigned short* A, unsigned short* As,
                                           int r0, int nrows, int tid) {
#pragma unroll
  for (int t = 0; t < 4; ++t) {
    int v = t * 256 + tid;
    int row = v >> 4, cc = v & 15;
    int gr = r0 + row;
    uint4 val = make_uint4(0, 0, 0, 0);
    if (gr < nrows) val = ((const uint4*)A)[(size_t)gr * 16 + cc];
    *(uint4*)&As[row * LDSW + cc * 8] = val;
  }
}

// ---------- batched pair GEMM: two independent A@W ----------
template <bool BIAS, bool RELU, int OM>
__global__ __launch_bounds__(256) void gemm2_mfma(const unsigned short* __restrict__ A0,
                                                  const unsigned short* __restrict__ A1,
                                                  const short8* __restrict__ Wp0,
                                                  const short8* __restrict__ Wp1,
                                                  const float* __restrict__ b0,
                                                  const float* __restrict__ b1,
                                                  void* __restrict__ o0, void* __restrict__ o1,
                                                  int nrows, int nblk) {
  __shared__ unsigned short As[64 * LDSW];
  int b = blockIdx.x;
  const unsigned short* A = A0;
  const short8* Wp = Wp0;
  const float* bias = b0;
  void* o = o0;
  if (b >= nblk) {
    b -= nblk; A = A1; Wp = Wp1; bias = b1; o = o1;
  }
  const int r0 = b * 64;
  stage_bf16(A, As, r0, nrows, threadIdx.x);
  __syncthreads();
  gemm_core<BIAS, RELU, OM>(As, Wp, bias, o, r0, nrows, threadIdx.x);
}

// ---------- 3 GEMMs sharing one fp32-A tile: fp8 outs to pair-half0 of P1,P2; fp32 out2 ----
__global__ __launch_bounds__(256) void gemm3_mfma(const float* __restrict__ A,
                                                  const short8* __restrict__ Wp,  // mats 0,1,2
                                                  const float* __restrict__ bias2,
                                                  unsigned char* __restrict__ p1,
                                                  unsigned char* __restrict__ p2,
                                                  float* __restrict__ out2, int nrows) {
  __shared__ unsigned short As[64 * LDSW];
  const int tid = threadIdx.x;
  const int r0 = blockIdx.x * 64;
#pragma unroll
  for (int t = 0; t < 8; ++t) {
    int v = t * 256 + tid;
    int row = v >> 5, c4 = v & 31;  // float4 chunk
    int gr = r0 + row;
    float4 val = make_float4(0.f, 0.f, 0.f, 0.f);
    if (gr < nrows) val = ((const float4*)A)[(size_t)gr * 32 + c4];
    ushort4 o;
    o.x = f2bf(val.x); o.y = f2bf(val.y); o.z = f2bf(val.z); o.w = f2bf(val.w);
    *(ushort4*)&As[row * LDSW + c4 * 4] = o;
  }
  __syncthreads();
  const int wave = tid >> 6, lane = tid & 63;
  const int quad = lane >> 4, l15 = lane & 15;
  const int rw = r0 + wave * 16;
  f32x4 acc[3][8];
#pragma unroll
  for (int m = 0; m < 3; ++m)
#pragma unroll
    for (int c = 0; c < 8; ++c) acc[m][c] = (f32x4){0.f, 0.f, 0.f, 0.f};
#pragma unroll
  for (int s = 0; s < 4; ++s) {
    short8 a = *(const short8*)&As[(wave * 16 + l15) * LDSW + s * 32 + quad * 8];
#pragma unroll
    for (int m = 0; m < 3; ++m)
#pragma unroll
      for (int c = 0; c < 8; ++c) {
        short8 b = Wp[(size_t)m * 2048 + (s * 8 + c) * 64 + lane];
        acc[m][c] = __builtin_amdgcn_mfma_f32_16x16x32_bf16(a, b, acc[m][c], 0, 0, 0);
      }
  }
#pragma unroll
  for (int c = 0; c < 8; ++c) {
    int col = c * 16 + l15;
    float bv = bias2[col];
#pragma unroll
    for (int r = 0; r < 4; ++r) {
      int grow = rw + quad * 4 + r;
      if (grow < nrows) {
        p1[(size_t)grow * 256 + col] = fp8_enc1(acc[0][c][r]);
        p2[(size_t)grow * 256 + col] = fp8_enc1(acc[1][c][r]);
        out2[(size_t)grow * 128 + col] = acc[2][c][r] + bv;
      }
    }
  }
}

// ---------- paired gather (CSR), fp8-pair input ----------
// Pair layout: [node][2][128] fp8 = 256 B/row-pair; lane l of 32: half=l>>4, colgrp=l&15.
// MODE 0: y[i] = wv[i]*(wv[i]*x[i] + sum_s wv[s]*x[s])   (GCN w/ self-loop)
// MODE 1: y[i] = wv[i]*sum_s x[s]                         (hypergraph halves)
template <int MODE, bool OUTFP8>
__device__ __forceinline__ void gpair_body(const uint2* __restrict__ xp,
                                           unsigned short* __restrict__ y1,
                                           unsigned short* __restrict__ y2,
                                           uint2* __restrict__ yp,
                                           const int* __restrict__ offs,
                                           const int* __restrict__ cnt,
                                           const int* __restrict__ slots,
                                           const float* __restrict__ wv, int blk) {
  int node = blk * 8 + (threadIdx.x >> 5);
  if (node >= NN) return;
  int l = threadIdx.x & 31;
  int st = offs[node], n = cnt[node];
  float acc[8];
#pragma unroll
  for (int i = 0; i < 8; ++i) acc[i] = 0.f;
  for (int p = 0; p < n; ++p) {
    int s = slots[st + p];
    uint2 v = xp[(size_t)s * 32 + l];
    float f[8];
    fp8x8_dec(v, f);
    if (MODE == 0) {
      float w = wv[s];
#pragma unroll
      for (int i = 0; i < 8; ++i) acc[i] = fmaf(w, f[i], acc[i]);
    } else {
#pragma unroll
      for (int i = 0; i < 8; ++i) acc[i] += f[i];
    }
  }
  float sc = wv[node];
  if (MODE == 0) {
    uint2 v = xp[(size_t)node * 32 + l];
    float f[8];
    fp8x8_dec(v, f);
#pragma unroll
    for (int i = 0; i < 8; ++i) acc[i] = sc * fmaf(sc, f[i], acc[i]);
  } else {
#pragma unroll
    for (int i = 0; i < 8; ++i) acc[i] *= sc;
  }
  if (OUTFP8) {
    yp[(size_t)node * 32 + l] = fp8x8_enc(acc);
  } else {
    unsigned short* y = (l < 16) ? y1 : y2;
    int cg = l & 15;
    uint4 o;
    o.x = ((unsigned)f2bf(acc[1]) << 16) | f2bf(acc[0]);
    o.y = ((unsigned)f2bf(acc[3]) << 16) | f2bf(acc[2]);
    o.z = ((unsigned)f2bf(acc[5]) << 16) | f2bf(acc[4]);
    o.w = ((unsigned)f2bf(acc[7]) << 16) | f2bf(acc[6]);
    *(uint4*)&y[(size_t)node * 128 + cg * 8] = o;
  }
}

// merged: pass1 (GCN, MODE0, CSR1, bf16 outs) + pass2 (HG-he, MODE1, CSR2, fp8-pair out)
__global__ void dgather12_k(const uint2* __restrict__ xp1, unsigned short* __restrict__ y1a,
                            unsigned short* __restrict__ y1b, const uint2* __restrict__ xp2,
                            uint2* __restrict__ yp3, const int* __restrict__ offs,
                            const int* __restrict__ cnt, const int* __restrict__ slots,
                            const float* __restrict__ dinv, const float* __restrict__ Binv,
                            int nblk) {
  int b = blockIdx.x;
  if (b < nblk)
    gpair_body<0, false>(xp1, y1a, y1b, nullptr, offs, cnt, slots, dinv, b);
  else
    gpair_body<1, true>(xp2, nullptr, nullptr, yp3, offs + NN, cnt + NN, slots, Binv,
                        b - nblk);
}

__global__ void dgather3_k(const uint2* __restrict__ xp, unsigned short* __restrict__ y1,
                           unsigned short* __restrict__ y2, const int* __restrict__ offs,
                           const int* __restrict__ cnt, const int* __restrict__ slots,
                           const float* __restrict__ wv) {
  gpair_body<1, false>(xp, y1, y2, nullptr, offs + 2 * NN, cnt + 2 * NN, slots, wv,
                       blockIdx.x);
}

// ---------- fused: fuse(analytic-query, conv) + residual + relu -> bf16 (batched x2) ----------
__device__ __forceinline__ void fuse_add_body(const unsigned short* __restrict__ g,
                                              const unsigned short* __restrict__ gr,
                                              const float* __restrict__ svec,
                                              const float* __restrict__ dscale,
                                              const float* __restrict__ Wq,
                                              const float* __restrict__ bq,
                                              const float* __restrict__ bm,
                                              const float* __restrict__ aq,
                                              const float* __restrict__ am,
                                              const float* __restrict__ bres,
                                              unsigned short* __restrict__ out, int blk) {
  int row = blk * 4 + (threadIdx.x >> 6);
  if (row >= NN) return;
  int lane = threadIdx.x & 63;
  int c0 = lane, c1 = lane + 64;
  float s = svec[row];
  if (dscale) s *= dscale[row];
  float hq0 = fmaxf(fmaf(s, Wq[c0], bq[c0]), 0.f);
  float hq1 = fmaxf(fmaf(s, Wq[c1], bq[c1]), 0.f);
  float h0 = fmaxf(bf2f(g[(size_t)row * 128 + c0]) + bm[c0], 0.f);
  float h1 = fmaxf(bf2f(g[(size_t)row * 128 + c1]) + bm[c1], 0.f);
  float dq = wsum64(hq0 * aq[c0] + hq1 * aq[c1]);
  float dm = wsum64(h0 * am[c0] + h1 * am[c1]);
  float mx = fmaxf(dq, dm);
  float e0 = expf(dq - mx), e1 = expf(dm - mx);
  float w0 = e0 / (e0 + e1), w1 = 1.f - w0;
  float r0 = fmaxf(w0 * hq0 + w1 * h0 + bf2f(gr[(size_t)row * 128 + c0]) + bres[c0], 0.f);
  float r1 = fmaxf(w0 * hq1 + w1 * h1 + bf2f(gr[(size_t)row * 128 + c1]) + bres[c1], 0.f);
  out[(size_t)row * 128 + c0] = f2bf(r0);
  out[(size_t)row * 128 + c1] = f2bf(r1);
}

__global__ void fuse_add2_k(const unsigned short* gA, const unsigned short* grA,
                            const float* svA, const float* dsA, const float* WqA,
                            const float* bqA, const float* bmA, const float* aqA,
                            const float* amA, const float* brA, unsigned short* outA,
                            const unsigned short* gB, const unsigned short* grB,
                            const float* svB, const float* dsB, const float* WqB,
                            const float* bqB, const float* bmB, const float* aqB,
                            const float* amB, const float* brB, unsigned short* outB,
                            int nblk) {
  int b = blockIdx.x;
  if (b < nblk)
    fuse_add_body(gA, grA, svA, dsA, WqA, bqA, bmA, aqA, amA, brA, outA, b);
  else
    fuse_add_body(gB, grB, svB, dsB, WqB, bqB, bmB, aqB, amB, brB, outB, b - nblk);
}

// ---------- fuse2: hf_ and hfh_ from analytic querys2 and feats2 -> bf16 ----------
__global__ void fuse2_k(const float* __restrict__ f2, const int* __restrict__ qp,
                        const float* __restrict__ Wlq, const float* __restrict__ blq,
                        const float* __restrict__ aq1, const float* __restrict__ a1,
                        const float* __restrict__ aq2, const float* __restrict__ a2,
                        unsigned short* __restrict__ out1, unsigned short* __restrict__ out2) {
  int row = blockIdx.x * 4 + (threadIdx.x >> 6);
  if (row >= NN) return;
  int lane = threadIdx.x & 63;
  int c0 = lane, c1 = lane + 64;
  int q = *qp;
  float q20 = blq[c0] + ((row == q) ? Wlq[c0] : 0.f);
  float q21 = blq[c1] + ((row == q) ? Wlq[c1] : 0.f);
  float f0 = f2[(size_t)row * 128 + c0];
  float f1 = f2[(size_t)row * 128 + c1];
  float dq1 = wsum64(q20 * aq1[c0] + q21 * aq1[c1]);
  float df1 = wsum64(f0 * a1[c0] + f1 * a1[c1]);
  float dq2 = wsum64(q20 * aq2[c0] + q21 * aq2[c1]);
  float df2 = wsum64(f0 * a2[c0] + f1 * a2[c1]);
  {
    float mx = fmaxf(dq1, df1);
    float e0 = expf(dq1 - mx), e1 = expf(df1 - mx);
    float w0 = e0 / (e0 + e1), w1 = 1.f - w0;
    out1[(size_t)row * 128 + c0] = f2bf(w0 * q20 + w1 * f0);
    out1[(size_t)row * 128 + c1] = f2bf(w0 * q21 + w1 * f1);
  }
  {
    float mx = fmaxf(dq2, df2);
    float e0 = expf(dq2 - mx), e1 = expf(df2 - mx);
    float w0 = e0 / (e0 + e1), w1 = 1.f - w0;
    out2[(size_t)row * 128 + c0] = f2bf(w0 * q20 + w1 * f0);
    out2[(size_t)row * 128 + c1] = f2bf(w0 * q21 + w1 * f1);
  }
}

// ---------- q-row norms (bf16 z) ----------
__global__ void qnorm_k(const unsigned short* __restrict__ z,
                        const unsigned short* __restrict__ za, const int* __restrict__ qp,
                        float* __restrict__ scal) {
  int lane = threadIdx.x & 63;
  int q = *qp;
  float zq0 = bf2f(z[(size_t)q * 128 + lane]), zq1 = bf2f(z[(size_t)q * 128 + lane + 64]);
  float zaq0 = bf2f(za[(size_t)q * 128 + lane]), zaq1 = bf2f(za[(size_t)q * 128 + lane + 64]);
  float nq = wsum64(zq0 * zq0 + zq1 * zq1);
  float naq = wsum64(zaq0 * zaq0 + zaq1 * zaq1);
  if (lane == 0) {
    scal[11] = sqrtf(nq);
    scal[12] = sqrtf(naq);
  }
}

// ---------- per-row cosine logits (bf16 z, no atomics) ----------
__global__ void sim_k(const unsigned short* __restrict__ z,
                      const unsigned short* __restrict__ za, const int* __restrict__ qp,
                      const float* __restrict__ scal, float4* __restrict__ simbuf,
                      float* __restrict__ scal_out) {
  int row = blockIdx.x * 4 + (threadIdx.x >> 6);
  if (row >= NN) return;
  int lane = threadIdx.x & 63;
  int c0 = lane, c1 = lane + 64;
  int q = *qp;
  float zi0 = bf2f(z[(size_t)row * 128 + c0]), zi1 = bf2f(z[(size_t)row * 128 + c1]);
  float zai0 = bf2f(za[(size_t)row * 128 + c0]), zai1 = bf2f(za[(size_t)row * 128 + c1]);
  float zq0 = bf2f(z[(size_t)q * 128 + c0]), zq1 = bf2f(z[(size_t)q * 128 + c1]);
  float zaq0 = bf2f(za[(size_t)q * 128 + c0]), zaq1 = bf2f(za[(size_t)q * 128 + c1]);
  float nzi = wsum64(zi0 * zi0 + zi1 * zi1);
  float nzai = wsum64(zai0 * zai0 + zai1 * zai1);
  float d1 = wsum64(zi0 * zq0 + zi1 * zq1);
  float d2 = wsum64(zai0 * zaq0 + zai1 * zaq1);
  float d3 = wsum64(zai0 * zq0 + zai1 * zq1);
  float d4 = wsum64(zi0 * zaq0 + zi1 * zaq1);
  if (lane == 0) {
    float ni = sqrtf(nzi), nai = sqrtf(nzai);
    float nq = scal[11], naq = scal[12];
    float c1_ = d1 / fmaxf(ni * nq, 1e-8f) * TAU_INV;
    float ca1 = d2 / fmaxf(nai * naq, 1e-8f) * TAU_INV;
    float c2_ = d3 / fmaxf(nai * nq, 1e-8f) * TAU_INV;
    float ca2 = d4 / fmaxf(ni * naq, 1e-8f) * TAU_INV;
    simbuf[row] = make_float4(c1_, ca1, c2_, ca2);
    if (row == q) {
      scal_out[9] = c2_;
      scal_out[10] = ca2;
    }
  }
}

__global__ __launch_bounds__(256) void reduce_sim_k(const float4* __restrict__ simbuf,
                                                    const int* __restrict__ maskI,
                                                    float* __restrict__ scal) {
  float acc[9];
#pragma unroll
  for (int i = 0; i < 9; ++i) acc[i] = 0.f;
  for (int row = blockIdx.x * 256 + threadIdx.x; row < NN; row += gridDim.x * 256) {
    float4 v = simbuf[row];
    acc[0] += expf(v.x);
    acc[1] += expf(v.y);
    acc[2] += expf(v.z);
    acc[3] += expf(v.w);
    if (maskI[row]) {
      acc[4] += v.x; acc[5] += v.y; acc[6] += v.z; acc[7] += v.w;
      acc[8] += 1.0f;
    }
  }
  __shared__ float s[9][4];
  int lane = threadIdx.x & 63, wv = threadIdx.x >> 6;
#pragma unroll
  for (int i = 0; i < 9; ++i) {
    float r = wsum64(acc[i]);
    if (lane == 0) s[i][wv] = r;
  }
  __syncthreads();
  if (threadIdx.x < 9) {
    float r = s[threadIdx.x][0] + s[threadIdx.x][1] + s[threadIdx.x][2] + s[threadIdx.x][3];
    atomicAdd(&scal[threadIdx.x], r);
  }
}

__global__ void final_k(const float* __restrict__ scal, float* __restrict__ out) {
  if (threadIdx.x != 0 || blockIdx.x != 0) return;
  float S1 = scal[0], Sa1 = scal[1], S2 = scal[2], Sa2 = scal[3];
  float L1 = scal[4], La1 = scal[5], L2 = scal[6], La2 = scal[7];
  float NM = scal[8], Q2 = scal[9], Qa2 = scal[10];
  float intra = 0.5f * ((logf(S1) - L1 / NM) + (logf(Sa1) - La1 / NM));
  float inter = 0.5f * ((logf(S2) - L2 / NM) + (logf(Sa2) - La2 / NM));
  float unsup = 0.5f * (logf(S2) - Q2) + 0.5f * (logf(Sa2) - Qa2);
  out[0] = intra + 0.5f * inter + 0.5f * unsup;  // ALPHA=0.5, LAM=0.5
}

// ---------- host ----------
extern "C" void kernel_launch(void* const* d_in, const int* in_sizes, int n_in,
                              void* d_out, int out_size, void* d_ws, size_t ws_size,
                              hipStream_t stream) {
  const float* feats = (const float*)d_in[0];
  const int* ei = (const int*)d_in[1];
  const int* ea = (const int*)d_in[2];
  const int* pos = (const int*)d_in[3];
  const int* qp = (const int*)d_in[4];
  const float* Wq0 = (const float*)d_in[5];
  const float* bq0 = (const float*)d_in[6];
  const float* W0 = (const float*)d_in[7];
  const float* b0 = (const float*)d_in[8];
  const float* Whq0 = (const float*)d_in[9];
  const float* bhq0 = (const float*)d_in[10];
  const float* Wh0 = (const float*)d_in[11];
  const float* bh0 = (const float*)d_in[12];
  const float* Wf0 = (const float*)d_in[13];
  const float* bf0 = (const float*)d_in[14];
  const float* Wfh0 = (const float*)d_in[15];
  const float* bfh0 = (const float*)d_in[16];
  const float* aq0 = (const float*)d_in[17];
  const float* a0 = (const float*)d_in[18];
  const float* ahq0 = (const float*)d_in[19];
  const float* ah0 = (const float*)d_in[20];
  const float* aq_ = (const float*)d_in[21];
  const float* a_ = (const float*)d_in[22];
  const float* ahq_ = (const float*)d_in[23];
  const float* ah_ = (const float*)d_in[24];
  const float* Wlq = (const float*)d_in[25];
  const float* blq = (const float*)d_in[26];
  const float* Wlf = (const float*)d_in[27];
  const float* blf = (const float*)d_in[28];
  const float* Wm1 = (const float*)d_in[29];
  const float* bm1 = (const float*)d_in[30];
  const float* Wm2 = (const float*)d_in[31];
  const float* bm2 = (const float*)d_in[32];

  char* ws = (char*)d_ws;
  size_t off = 0;
  auto take = [&](size_t bytes) -> void* {
    void* p = ws + off;
    off = (off + bytes + 255) & ~(size_t)255;
    return p;
  };
  // ---- zero region ----
  int* cnt3 = (int*)take(3 * NN * 4);
  int* cursor3 = (int*)take(3 * NN * 4);
  int* aux = (int*)take(1024 * 4);
  int* maskI = (int*)take(NN * 4);
  float* s_hq = (float*)take(NN * 4);
  float* cntq = (float*)take(NN * 4);
  float* s_hgq = (float*)take(NN * 4);
  float* scal = (float*)take(64 * 4);
  size_t zero_end = off;
  // ---- non-zeroed scratch ----
  int* offs3 = (int*)take(3 * NN * 4);
  int* slots = (int*)take((size_t)3 * EE * 4);
  float* dinv = (float*)take(NN * 4);
  float* Binv = (float*)take(NN * 4);
  float* Dninv = (float*)take(NN * 4);
  float4* simbuf = (float4*)take((size_t)NN * 16);
  unsigned short* Wpack = (unsigned short*)take((size_t)7 * 16384 * 2);
  const size_t BFSZ = (size_t)NN * HH * 2;
  unsigned short* B0 = (unsigned short*)take(BFSZ);
  unsigned short* B1 = (unsigned short*)take(BFSZ);
  unsigned short* B2 = (unsigned short*)take(BFSZ);
  unsigned short* B3 = (unsigned short*)take(BFSZ);
  unsigned short* B4 = (unsigned short*)take(BFSZ);
  unsigned short* B5 = (unsigned short*)take(BFSZ);
  unsigned char* P1 = (unsigned char*)take((size_t)NN * 256);  // fp8 pair [node][2][128]
  unsigned char* P2 = (unsigned char*)take((size_t)NN * 256);
  unsigned char* P3 = (unsigned char*)take((size_t)NN * 256);
  float* F0 = (float*)take((size_t)NN * HH * 4);

  const int NB = (NN + 255) / 256;
  const int M3 = 3 * NN;
  const int SB = (M3 + 255) / 256;
  const int GMB = (NN + 63) / 64;    // gemm blocks (64 rows each)
  const int GTB = (NN + 7) / 8;      // gather blocks
  const int RB = (NN + 3) / 4;       // row-wave blocks
  const short8* Wp = (const short8*)Wpack;

  hipMemsetAsync(d_ws, 0, zero_end, stream);
  // CSR build (XCD-partitioned) + degree vectors + analytic query coefficients
  count_k<<<512, 256, 0, stream>>>(ei, ea, qp, cnt3, cntq);
  derive_k<<<NB, 256, 0, stream>>>(cnt3, dinv, Binv, Dninv);
  scan1<<<SB, 256, 0, stream>>>(cnt3, offs3, aux, M3);
  scan2<<<1, 1024, 0, stream>>>(aux, SB);
  scan3<<<SB, 256, 0, stream>>>(offs3, aux, M3);
  fill_k<<<512, 256, 0, stream>>>(ei, ea, qp, offs3, cursor3, slots, dinv, Binv, cntq,
                                  s_hq, s_hgq);
  mask_k<<<1, 128, 0, stream>>>(pos, qp, maskI, s_hq, dinv);

  // dense prep
  pack_k<<<(7 * 2048 + 255) / 256, 256, 0, stream>>>(W0, Wh0, Wlf, Wf0, Wfh0, Wm1, Wm2,
                                                     Wpack);
  // feats @ {W0, Wh0, Wlf}: xw0 -> P1.half0 (fp8), xwh -> P2.half0 (fp8), feats2 -> F0
  gemm3_mfma<<<GMB, 256, 0, stream>>>(feats, Wp, blf, P1, P2, F0, NN);
  // hf_ = B3, hfh_ = B4
  fuse2_k<<<RB, 256, 0, stream>>>(F0, qp, Wlq, blq, aq_, a_, ahq_, ah_, B3, B4);
  // xwf -> P1.half1 ; xwfh -> P2.half1  (fp8, batched)
  gemm2_mfma<false, false, 2><<<2 * GMB, 256, 0, stream>>>(
      B3, B4, Wp + (size_t)3 * 2048, Wp + (size_t)4 * 2048, nullptr, nullptr, P1 + 128,
      P2 + 128, NN, GMB);
  // gathers: pass1 GCN P1 -> (B0=g0, B1=gf) bf16 ; pass2 HG-he P2 -> P3 fp8  [merged]
  dgather12_k<<<2 * GTB, 256, 0, stream>>>((const uint2*)P1, B0, B1, (const uint2*)P2,
                                           (uint2*)P3, offs3, cnt3, slots, dinv, Binv, GTB);
  // pass3 HG-node P3 -> (B2, B5) bf16
  dgather3_k<<<GTB, 256, 0, stream>>>((const uint2*)P3, B2, B5, offs3, cnt3, slots, Dninv);
  // hf = B3 ; h_augf = B4  (batched fuse+residual+relu; B3/B4 free after gemm2 above)
  fuse_add2_k<<<2 * RB, 256, 0, stream>>>(
      B0, B1, s_hq, nullptr, Wq0, bq0, b0, aq0, a0, bf0, B3,
      B2, B5, s_hgq, Dninv, Whq0, bhq0, bh0, ahq0, ah0, bfh0, B4, RB);
  // MLPs (batched per layer): L1: (B3->B0),(B4->B1) ; L2: (B0->B2=z),(B1->B5=z_aug) bf16
  gemm2_mfma<true, true, 1><<<2 * GMB, 256, 0, stream>>>(
      B3, B4, Wp + (size_t)5 * 2048, Wp + (size_t)5 * 2048, bm1, bm1, B0, B1, NN, GMB);
  gemm2_mfma<true, false, 1><<<2 * GMB, 256, 0, stream>>>(
      B0, B1, Wp + (size_t)6 * 2048, Wp + (size_t)6 * 2048, bm2, bm2, B2, B5, NN, GMB);
  // loss
  qnorm_k<<<1, 64, 0, stream>>>(B2, B5, qp, scal);
  sim_k<<<RB, 256, 0, stream>>>(B2, B5, qp, scal, simbuf, scal);
  reduce_sim_k<<<64, 256, 0, stream>>>(simbuf, maskI, scal);
  final_k<<<1, 64, 0, stream>>>(scal, (float*)d_out);
}

// Round 6
// 610.590 us; speedup vs baseline: 5.9570x; 1.0285x over previous
//
#include <hip/hip_runtime.h>

#define NN 50000
#define EE 600000
#define HH 128
#define TAU_INV 2.0f   // 1/TAU, TAU=0.5
#define PSZ 6250       // NN / 8 partitions (node range per XCD)

typedef __attribute__((ext_vector_type(8))) short short8;
typedef __attribute__((ext_vector_type(4))) float f32x4;
typedef __attribute__((ext_vector_type(2))) float floatx2;

// ---------- helpers ----------
__device__ __forceinline__ float wsum64(float v) {
#pragma unroll
  for (int m = 32; m >= 1; m >>= 1) v += __shfl_xor(v, m, 64);
  return v;
}
__device__ __forceinline__ unsigned short f2bf(float f) {
  unsigned u = __builtin_bit_cast(unsigned, f);
  u = u + 0x7FFFu + ((u >> 16) & 1u);
  return (unsigned short)(u >> 16);
}
__device__ __forceinline__ float bf2f(unsigned short h) {
  unsigned u = ((unsigned)h) << 16;
  return __builtin_bit_cast(float, u);
}
// fp8 e4m3 (OCP) via gfx950 HW converts
__device__ __forceinline__ unsigned char fp8_enc1(float v) {
  int p = __builtin_amdgcn_cvt_pk_fp8_f32(v, v, 0, false);
  return (unsigned char)(p & 0xFF);
}
__device__ __forceinline__ void fp8x8_dec(uint2 v, float* f) {
  floatx2 a = __builtin_amdgcn_cvt_pk_f32_fp8(v.x, false);
  floatx2 b = __builtin_amdgcn_cvt_pk_f32_fp8(v.x, true);
  floatx2 c = __builtin_amdgcn_cvt_pk_f32_fp8(v.y, false);
  floatx2 d = __builtin_amdgcn_cvt_pk_f32_fp8(v.y, true);
  f[0] = a.x; f[1] = a.y; f[2] = b.x; f[3] = b.y;
  f[4] = c.x; f[5] = c.y; f[6] = d.x; f[7] = d.y;
}
__device__ __forceinline__ uint2 fp8x8_enc(const float* f) {
  int w0 = __builtin_amdgcn_cvt_pk_fp8_f32(f[0], f[1], 0, false);
  w0 = __builtin_amdgcn_cvt_pk_fp8_f32(f[2], f[3], w0, true);
  int w1 = __builtin_amdgcn_cvt_pk_fp8_f32(f[4], f[5], 0, false);
  w1 = __builtin_amdgcn_cvt_pk_fp8_f32(f[6], f[7], w1, true);
  return make_uint2((unsigned)w0, (unsigned)w1);
}

// ---------- CSR build (XCD-partitioned: p = blockIdx & 7 owns nodes [p*PSZ,(p+1)*PSZ)) ----
__global__ void count_k(const int* __restrict__ ei, const int* __restrict__ ea,
                        const int* __restrict__ qp, int* __restrict__ cnt,
                        float* __restrict__ cntq) {
  const int p = blockIdx.x & 7;
  const int lo = p * PSZ, hi = lo + PSZ;
  const int q = *qp;
  const int stride = (gridDim.x >> 3) * 256;
  for (int e = (blockIdx.x >> 3) * 256 + threadIdx.x; e < EE; e += stride) {
    int dst = ei[EE + e];
    if (dst >= lo && dst < hi) atomicAdd(&cnt[dst], 1);
    int node = ea[e], he = ea[EE + e];
    if (he >= lo && he < hi) {
      atomicAdd(&cnt[NN + he], 1);
      if (node == q) atomicAdd(&cntq[he], 1.0f);
    }
    if (node >= lo && node < hi) atomicAdd(&cnt[2 * NN + node], 1);
  }
}

__global__ void derive_k(const int* __restrict__ cnt, float* __restrict__ dinv,
                         float* __restrict__ Binv, float* __restrict__ Dninv) {
  int i = blockIdx.x * 256 + threadIdx.x;
  if (i >= NN) return;
  dinv[i] = rsqrtf((float)(cnt[i] + 1));  // deg includes self-loop
  int b = cnt[NN + i];
  Binv[i] = (b > 0) ? 1.0f / (float)b : 0.0f;
  int d = cnt[2 * NN + i];
  Dninv[i] = (d > 0) ? 1.0f / (float)d : 0.0f;
}

__global__ void scan1(const int* __restrict__ cnt, int* __restrict__ offs,
                      int* __restrict__ aux, int M) {
  __shared__ int s[256];
  int tid = threadIdx.x, gid = blockIdx.x * 256 + tid;
  int v = (gid < M) ? cnt[gid] : 0;
  s[tid] = v;
  __syncthreads();
  for (int d = 1; d < 256; d <<= 1) {
    int t = (tid >= d) ? s[tid - d] : 0;
    __syncthreads();
    s[tid] += t;
    __syncthreads();
  }
  if (gid < M) offs[gid] = s[tid] - v;  // exclusive
  if (tid == 255) aux[blockIdx.x] = s[255];
}

__global__ void scan2(int* __restrict__ aux, int nb) {
  __shared__ int s[1024];
  int tid = threadIdx.x;
  int v = (tid < nb) ? aux[tid] : 0;
  s[tid] = v;
  __syncthreads();
  for (int d = 1; d < 1024; d <<= 1) {
    int t = (tid >= d) ? s[tid - d] : 0;
    __syncthreads();
    s[tid] += t;
    __syncthreads();
  }
  if (tid < nb) aux[tid] = s[tid] - v;
}

// scan3 + mask_k merged (block 0 does mask/self-loop work; all adds, order-free vs fill_k)
__global__ void scan3(int* __restrict__ offs, const int* __restrict__ aux, int M,
                      const int* __restrict__ pos, const int* __restrict__ qp,
                      int* __restrict__ maskI, float* __restrict__ s_hq,
                      const float* __restrict__ dinv) {
  int gid = blockIdx.x * 256 + threadIdx.x;
  if (gid < M) offs[gid] += aux[blockIdx.x];
  if (blockIdx.x == 0) {
    int t = threadIdx.x;
    if (t < 100) maskI[pos[t]] = 1;
    __syncthreads();
    if (t == 0) {
      int q = *qp;
      maskI[q] = 0;
      atomicAdd(&s_hq[q], dinv[q] * dinv[q]);  // self-loop contribution of query gcn
    }
  }
}

// fill CSR slots + analytic query coefficients, XCD-partitioned
__global__ void fill_k(const int* __restrict__ ei, const int* __restrict__ ea,
                       const int* __restrict__ qp, const int* __restrict__ offs,
                       int* __restrict__ cursor, int* __restrict__ slots,
                       const float* __restrict__ dinv, const float* __restrict__ Binv,
                       const float* __restrict__ cntq, float* __restrict__ s_hq,
                       float* __restrict__ s_hgq) {
  const int p = blockIdx.x & 7;
  const int lo = p * PSZ, hi = lo + PSZ;
  const int q = *qp;
  const int stride = (gridDim.x >> 3) * 256;
  for (int e = (blockIdx.x >> 3) * 256 + threadIdx.x; e < EE; e += stride) {
    int src = ei[e], dst = ei[EE + e];
    if (dst >= lo && dst < hi) {
      int pp = offs[dst] + atomicAdd(&cursor[dst], 1);
      slots[pp] = src;
      if (src == q) atomicAdd(&s_hq[dst], dinv[q] * dinv[dst]);
    }
    int node = ea[e], he = ea[EE + e];
    if (he >= lo && he < hi) {
      int p2 = offs[NN + he] + atomicAdd(&cursor[NN + he], 1);
      slots[p2] = node;
    }
    if (node >= lo && node < hi) {
      int p3 = offs[2 * NN + node] + atomicAdd(&cursor[2 * NN + node], 1);
      slots[p3] = he;
      float t = Binv[he] * cntq[he];
      if (t != 0.0f) atomicAdd(&s_hgq[node], t);
    }
  }
}

// ---------- pack 7 weight matrices into MFMA B-fragment order ----------
__global__ void pack_k(const float* __restrict__ W0, const float* __restrict__ Wh0,
                       const float* __restrict__ Wlf, const float* __restrict__ Wf0,
                       const float* __restrict__ Wfh0, const float* __restrict__ Wm1,
                       const float* __restrict__ Wm2, unsigned short* __restrict__ out) {
  int tid = blockIdx.x * 256 + threadIdx.x;
  if (tid >= 7 * 2048) return;
  int mat = tid >> 11, r = tid & 2047;
  int s = r >> 9, c = (r >> 6) & 7, lane = r & 63;
  const float* W = (mat == 0) ? W0 : (mat == 1) ? Wh0 : (mat == 2) ? Wlf
                 : (mat == 3) ? Wf0 : (mat == 4) ? Wfh0 : (mat == 5) ? Wm1 : Wm2;
  int k0 = 32 * s + (lane >> 4) * 8;
  int n = 16 * c + (lane & 15);
  unsigned short* o = out + (size_t)tid * 8;
#pragma unroll
  for (int j = 0; j < 8; ++j) o[j] = f2bf(W[(k0 + j) * 128 + n]);
}

#define LDSW 136  // 128 + 8 bf16 pad

// ---------- gemm core (A already staged in LDS as bf16) ----------
// OM: 0 = fp32 out (stride 128 f32), 1 = bf16 out (stride 128), 2 = fp8 out (uchar*, stride 256)
template <bool BIAS, bool RELU, int OM>
__device__ __forceinline__ void gemm_core(const unsigned short* As, const short8* Wp,
                                          const float* bias, void* outv, int r0, int nrows,
                                          int tid) {
  const int wave = tid >> 6, lane = tid & 63;
  const int quad = lane >> 4, l15 = lane & 15;
  const int rw = r0 + wave * 16;
  f32x4 acc[8];
#pragma unroll
  for (int c = 0; c < 8; ++c) acc[c] = (f32x4){0.f, 0.f, 0.f, 0.f};
#pragma unroll
  for (int s = 0; s < 4; ++s) {
    short8 a = *(const short8*)&As[(wave * 16 + l15) * LDSW + s * 32 + quad * 8];
#pragma unroll
    for (int c = 0; c < 8; ++c) {
      short8 b = Wp[(s * 8 + c) * 64 + lane];
      acc[c] = __builtin_amdgcn_mfma_f32_16x16x32_bf16(a, b, acc[c], 0, 0, 0);
    }
  }
#pragma unroll
  for (int c = 0; c < 8; ++c) {
    int col = c * 16 + l15;
    float bv = BIAS ? bias[col] : 0.f;
#pragma unroll
    for (int r = 0; r < 4; ++r) {
      int grow = rw + quad * 4 + r;
      if (grow < nrows) {
        float v = acc[c][r] + bv;
        if (RELU) v = fmaxf(v, 0.f);
        if (OM == 2)
          ((unsigned char*)outv)[(size_t)grow * 256 + col] = fp8_enc1(v);
        else if (OM == 1)
          ((unsigned short*)outv)[(size_t)grow * 128 + col] = f2bf(v);
        else
          ((float*)outv)[(size_t)grow * 128 + col] = v;
      }
    }
  }
}

__device__ __forceinline__ void stage_bf16(const unsigned short* A, unsigned short* As,
                                           int r0, int nrows, int tid) {
#pragma unroll
  for (int t = 0; t < 4; ++t) {
    int v = t * 256 + tid;
    int row = v >> 4, cc = v & 15;
    int gr = r0 + row;
    uint4 val = make_uint4(0, 0, 0, 0);
    if (gr < nrows) val = ((const uint4*)A)[(size_t)gr * 16 + cc];
    *(uint4*)&As[row * LDSW + cc * 8] = val;
  }
}

// ---------- batched pair GEMM: two independent A@W ----------
template <bool BIAS, bool RELU, int OM>
__global__ __launch_bounds__(256) void gemm2_mfma(const unsigned short* __restrict__ A0,
                                                  const unsigned short* __restrict__ A1,
                                                  const short8* __restrict__ Wp0,
                                                  const short8* __restrict__ Wp1,
                                                  const float* __restrict__ b0,
                                                  const float* __restrict__ b1,
                                                  void* __restrict__ o0, void* __restrict__ o1,
                                                  int nrows, int nblk) {
  __shared__ unsigned short As[64 * LDSW];
  int b = blockIdx.x;
  const unsigned short* A = A0;
  const short8* Wp = Wp0;
  const float* bias = b0;
  void* o = o0;
  if (b >= nblk) {
    b -= nblk; A = A1; Wp = Wp1; bias = b1; o = o1;
  }
  const int r0 = b * 64;
  stage_bf16(A, As, r0, nrows, threadIdx.x);
  __syncthreads();
  gemm_core<BIAS, RELU, OM>(As, Wp, bias, o, r0, nrows, threadIdx.x);
}

// ---------- 3 GEMMs sharing one fp32-A tile: fp8 outs to pair-half0 of P1,P2; bf16 out2 ----
__global__ __launch_bounds__(256) void gemm3_mfma(const float* __restrict__ A,
                                                  const short8* __restrict__ Wp,  // mats 0,1,2
                                                  const float* __restrict__ bias2,
                                                  unsigned char* __restrict__ p1,
                                                  unsigned char* __restrict__ p2,
                                                  unsigned short* __restrict__ out2,
                                                  int nrows) {
  __shared__ unsigned short As[64 * LDSW];
  const int tid = threadIdx.x;
  const int r0 = blockIdx.x * 64;
#pragma unroll
  for (int t = 0; t < 8; ++t) {
    int v = t * 256 + tid;
    int row = v >> 5, c4 = v & 31;  // float4 chunk
    int gr = r0 + row;
    float4 val = make_float4(0.f, 0.f, 0.f, 0.f);
    if (gr < nrows) val = ((const float4*)A)[(size_t)gr * 32 + c4];
    ushort4 o;
    o.x = f2bf(val.x); o.y = f2bf(val.y); o.z = f2bf(val.z); o.w = f2bf(val.w);
    *(ushort4*)&As[row * LDSW + c4 * 4] = o;
  }
  __syncthreads();
  const int wave = tid >> 6, lane = tid & 63;
  const int quad = lane >> 4, l15 = lane & 15;
  const int rw = r0 + wave * 16;
  f32x4 acc[3][8];
#pragma unroll
  for (int m = 0; m < 3; ++m)
#pragma unroll
    for (int c = 0; c < 8; ++c) acc[m][c] = (f32x4){0.f, 0.f, 0.f, 0.f};
#pragma unroll
  for (int s = 0; s < 4; ++s) {
    short8 a = *(const short8*)&As[(wave * 16 + l15) * LDSW + s * 32 + quad * 8];
#pragma unroll
    for (int m = 0; m < 3; ++m)
#pragma unroll
      for (int c = 0; c < 8; ++c) {
        short8 b = Wp[(size_t)m * 2048 + (s * 8 + c) * 64 + lane];
        acc[m][c] = __builtin_amdgcn_mfma_f32_16x16x32_bf16(a, b, acc[m][c], 0, 0, 0);
      }
  }
#pragma unroll
  for (int c = 0; c < 8; ++c) {
    int col = c * 16 + l15;
    float bv = bias2[col];
#pragma unroll
    for (int r = 0; r < 4; ++r) {
      int grow = rw + quad * 4 + r;
      if (grow < nrows) {
        p1[(size_t)grow * 256 + col] = fp8_enc1(acc[0][c][r]);
        p2[(size_t)grow * 256 + col] = fp8_enc1(acc[1][c][r]);
        out2[(size_t)grow * 128 + col] = f2bf(acc[2][c][r] + bv);
      }
    }
  }
}

// ---------- paired gather (CSR), fp8-pair input ----------
// Pair layout: [node][2][128] fp8 = 256 B/row-pair; lane l of 32: half=l>>4, colgrp=l&15.
// MODE 0: y[i] = wv[i]*(wv[i]*x[i] + sum_s wv[s]*x[s])   (GCN w/ self-loop)
// MODE 1: y[i] = wv[i]*sum_s x[s]                         (hypergraph halves)
template <int MODE, bool OUTFP8>
__device__ __forceinline__ void gpair_body(const uint2* __restrict__ xp,
                                           unsigned short* __restrict__ y1,
                                           unsigned short* __restrict__ y2,
                                           uint2* __restrict__ yp,
                                           const int* __restrict__ offs,
                                           const int* __restrict__ cnt,
                                           const int* __restrict__ slots,
                                           const float* __restrict__ wv, int blk) {
  int node = blk * 8 + (threadIdx.x >> 5);
  if (node >= NN) return;
  int l = threadIdx.x & 31;
  int st = offs[node], n = cnt[node];
  float acc[8];
#pragma unroll
  for (int i = 0; i < 8; ++i) acc[i] = 0.f;
  for (int p = 0; p < n; ++p) {
    int s = slots[st + p];
    uint2 v = xp[(size_t)s * 32 + l];
    float f[8];
    fp8x8_dec(v, f);
    if (MODE == 0) {
      float w = wv[s];
#pragma unroll
      for (int i = 0; i < 8; ++i) acc[i] = fmaf(w, f[i], acc[i]);
    } else {
#pragma unroll
      for (int i = 0; i < 8; ++i) acc[i] += f[i];
    }
  }
  float sc = wv[node];
  if (MODE == 0) {
    uint2 v = xp[(size_t)node * 32 + l];
    float f[8];
    fp8x8_dec(v, f);
#pragma unroll
    for (int i = 0; i < 8; ++i) acc[i] = sc * fmaf(sc, f[i], acc[i]);
  } else {
#pragma unroll
    for (int i = 0; i < 8; ++i) acc[i] *= sc;
  }
  if (OUTFP8) {
    yp[(size_t)node * 32 + l] = fp8x8_enc(acc);
  } else {
    unsigned short* y = (l < 16) ? y1 : y2;
    int cg = l & 15;
    uint4 o;
    o.x = ((unsigned)f2bf(acc[1]) << 16) | f2bf(acc[0]);
    o.y = ((unsigned)f2bf(acc[3]) << 16) | f2bf(acc[2]);
    o.z = ((unsigned)f2bf(acc[5]) << 16) | f2bf(acc[4]);
    o.w = ((unsigned)f2bf(acc[7]) << 16) | f2bf(acc[6]);
    *(uint4*)&y[(size_t)node * 128 + cg * 8] = o;
  }
}

// merged: pass1 (GCN, MODE0, CSR1, bf16 outs) + pass2 (HG-he, MODE1, CSR2, fp8-pair out)
__global__ void dgather12_k(const uint2* __restrict__ xp1, unsigned short* __restrict__ y1a,
                            unsigned short* __restrict__ y1b, const uint2* __restrict__ xp2,
                            uint2* __restrict__ yp3, const int* __restrict__ offs,
                            const int* __restrict__ cnt, const int* __restrict__ slots,
                            const float* __restrict__ dinv, const float* __restrict__ Binv,
                            int nblk) {
  int b = blockIdx.x;
  if (b < nblk)
    gpair_body<0, false>(xp1, y1a, y1b, nullptr, offs, cnt, slots, dinv, b);
  else
    gpair_body<1, true>(xp2, nullptr, nullptr, yp3, offs + NN, cnt + NN, slots, Binv,
                        b - nblk);
}

__global__ void dgather3_k(const uint2* __restrict__ xp, unsigned short* __restrict__ y1,
                           unsigned short* __restrict__ y2, const int* __restrict__ offs,
                           const int* __restrict__ cnt, const int* __restrict__ slots,
                           const float* __restrict__ wv) {
  gpair_body<1, false>(xp, y1, y2, nullptr, offs + 2 * NN, cnt + 2 * NN, slots, wv,
                       blockIdx.x);
}

// ---------- fused: fuse(analytic-query, conv) + residual + relu -> bf16 (batched x2) ----------
__device__ __forceinline__ void fuse_add_body(const unsigned short* __restrict__ g,
                                              const unsigned short* __restrict__ gr,
                                              const float* __restrict__ svec,
                                              const float* __restrict__ dscale,
                                              const float* __restrict__ Wq,
                                              const float* __restrict__ bq,
                                              const float* __restrict__ bm,
                                              const float* __restrict__ aq,
                                              const float* __restrict__ am,
                                              const float* __restrict__ bres,
                                              unsigned short* __restrict__ out, int blk) {
  int row = blk * 4 + (threadIdx.x >> 6);
  if (row >= NN) return;
  int lane = threadIdx.x & 63;
  int c0 = lane, c1 = lane + 64;
  float s = svec[row];
  if (dscale) s *= dscale[row];
  float hq0 = fmaxf(fmaf(s, Wq[c0], bq[c0]), 0.f);
  float hq1 = fmaxf(fmaf(s, Wq[c1], bq[c1]), 0.f);
  float h0 = fmaxf(bf2f(g[(size_t)row * 128 + c0]) + bm[c0], 0.f);
  float h1 = fmaxf(bf2f(g[(size_t)row * 128 + c1]) + bm[c1], 0.f);
  float dq = wsum64(hq0 * aq[c0] + hq1 * aq[c1]);
  float dm = wsum64(h0 * am[c0] + h1 * am[c1]);
  float mx = fmaxf(dq, dm);
  float e0 = expf(dq - mx), e1 = expf(dm - mx);
  float w0 = e0 / (e0 + e1), w1 = 1.f - w0;
  float r0 = fmaxf(w0 * hq0 + w1 * h0 + bf2f(gr[(size_t)row * 128 + c0]) + bres[c0], 0.f);
  float r1 = fmaxf(w0 * hq1 + w1 * h1 + bf2f(gr[(size_t)row * 128 + c1]) + bres[c1], 0.f);
  out[(size_t)row * 128 + c0] = f2bf(r0);
  out[(size_t)row * 128 + c1] = f2bf(r1);
}

__global__ void fuse_add2_k(const unsigned short* gA, const unsigned short* grA,
                            const float* svA, const float* dsA, const float* WqA,
                            const float* bqA, const float* bmA, const float* aqA,
                            const float* amA, const float* brA, unsigned short* outA,
                            const unsigned short* gB, const unsigned short* grB,
                            const float* svB, const float* dsB, const float* WqB,
                            const float* bqB, const float* bmB, const float* aqB,
                            const float* amB, const float* brB, unsigned short* outB,
                            int nblk) {
  int b = blockIdx.x;
  if (b < nblk)
    fuse_add_body(gA, grA, svA, dsA, WqA, bqA, bmA, aqA, amA, brA, outA, b);
  else
    fuse_add_body(gB, grB, svB, dsB, WqB, bqB, bmB, aqB, amB, brB, outB, b - nblk);
}

// ---------- fuse2: hf_ and hfh_ from analytic querys2 and feats2(bf16) -> bf16 ----------
__global__ void fuse2_k(const unsigned short* __restrict__ f2, const int* __restrict__ qp,
                        const float* __restrict__ Wlq, const float* __restrict__ blq,
                        const float* __restrict__ aq1, const float* __restrict__ a1,
                        const float* __restrict__ aq2, const float* __restrict__ a2,
                        unsigned short* __restrict__ out1, unsigned short* __restrict__ out2) {
  int row = blockIdx.x * 4 + (threadIdx.x >> 6);
  if (row >= NN) return;
  int lane = threadIdx.x & 63;
  int c0 = lane, c1 = lane + 64;
  int q = *qp;
  float q20 = blq[c0] + ((row == q) ? Wlq[c0] : 0.f);
  float q21 = blq[c1] + ((row == q) ? Wlq[c1] : 0.f);
  float f0 = bf2f(f2[(size_t)row * 128 + c0]);
  float f1 = bf2f(f2[(size_t)row * 128 + c1]);
  float dq1 = wsum64(q20 * aq1[c0] + q21 * aq1[c1]);
  float df1 = wsum64(f0 * a1[c0] + f1 * a1[c1]);
  float dq2 = wsum64(q20 * aq2[c0] + q21 * aq2[c1]);
  float df2 = wsum64(f0 * a2[c0] + f1 * a2[c1]);
  {
    float mx = fmaxf(dq1, df1);
    float e0 = expf(dq1 - mx), e1 = expf(df1 - mx);
    float w0 = e0 / (e0 + e1), w1 = 1.f - w0;
    out1[(size_t)row * 128 + c0] = f2bf(w0 * q20 + w1 * f0);
    out1[(size_t)row * 128 + c1] = f2bf(w0 * q21 + w1 * f1);
  }
  {
    float mx = fmaxf(dq2, df2);
    float e0 = expf(dq2 - mx), e1 = expf(df2 - mx);
    float w0 = e0 / (e0 + e1), w1 = 1.f - w0;
    out2[(size_t)row * 128 + c0] = f2bf(w0 * q20 + w1 * f0);
    out2[(size_t)row * 128 + c1] = f2bf(w0 * q21 + w1 * f1);
  }
}

// ---------- per-row cosine logits (bf16 z, q-norms computed locally) ----------
__global__ void sim_k(const unsigned short* __restrict__ z,
                      const unsigned short* __restrict__ za, const int* __restrict__ qp,
                      float4* __restrict__ simbuf, float* __restrict__ scal_out) {
  int row = blockIdx.x * 4 + (threadIdx.x >> 6);
  if (row >= NN) return;
  int lane = threadIdx.x & 63;
  int c0 = lane, c1 = lane + 64;
  int q = *qp;
  float zi0 = bf2f(z[(size_t)row * 128 + c0]), zi1 = bf2f(z[(size_t)row * 128 + c1]);
  float zai0 = bf2f(za[(size_t)row * 128 + c0]), zai1 = bf2f(za[(size_t)row * 128 + c1]);
  float zq0 = bf2f(z[(size_t)q * 128 + c0]), zq1 = bf2f(z[(size_t)q * 128 + c1]);
  float zaq0 = bf2f(za[(size_t)q * 128 + c0]), zaq1 = bf2f(za[(size_t)q * 128 + c1]);
  float nzi = wsum64(zi0 * zi0 + zi1 * zi1);
  float nzai = wsum64(zai0 * zai0 + zai1 * zai1);
  float nzq = wsum64(zq0 * zq0 + zq1 * zq1);
  float nzaq = wsum64(zaq0 * zaq0 + zaq1 * zaq1);
  float d1 = wsum64(zi0 * zq0 + zi1 * zq1);
  float d2 = wsum64(zai0 * zaq0 + zai1 * zaq1);
  float d3 = wsum64(zai0 * zq0 + zai1 * zq1);
  float d4 = wsum64(zi0 * zaq0 + zi1 * zaq1);
  if (lane == 0) {
    float ni = sqrtf(nzi), nai = sqrtf(nzai);
    float nq = sqrtf(nzq), naq = sqrtf(nzaq);
    float c1_ = d1 / fmaxf(ni * nq, 1e-8f) * TAU_INV;
    float ca1 = d2 / fmaxf(nai * naq, 1e-8f) * TAU_INV;
    float c2_ = d3 / fmaxf(nai * nq, 1e-8f) * TAU_INV;
    float ca2 = d4 / fmaxf(ni * naq, 1e-8f) * TAU_INV;
    simbuf[row] = make_float4(c1_, ca1, c2_, ca2);
    if (row == q) {
      scal_out[9] = c2_;
      scal_out[10] = ca2;
    }
  }
}

__global__ __launch_bounds__(256) void reduce_sim_k(const float4* __restrict__ simbuf,
                                                    const int* __restrict__ maskI,
                                                    float* __restrict__ scal) {
  float acc[9];
#pragma unroll
  for (int i = 0; i < 9; ++i) acc[i] = 0.f;
  for (int row = blockIdx.x * 256 + threadIdx.x; row < NN; row += gridDim.x * 256) {
    float4 v = simbuf[row];
    acc[0] += expf(v.x);
    acc[1] += expf(v.y);
    acc[2] += expf(v.z);
    acc[3] += expf(v.w);
    if (maskI[row]) {
      acc[4] += v.x; acc[5] += v.y; acc[6] += v.z; acc[7] += v.w;
      acc[8] += 1.0f;
    }
  }
  __shared__ float s[9][4];
  int lane = threadIdx.x & 63, wv = threadIdx.x >> 6;
#pragma unroll
  for (int i = 0; i < 9; ++i) {
    float r = wsum64(acc[i]);
    if (lane == 0) s[i][wv] = r;
  }
  __syncthreads();
  if (threadIdx.x < 9) {
    float r = s[threadIdx.x][0] + s[threadIdx.x][1] + s[threadIdx.x][2] + s[threadIdx.x][3];
    atomicAdd(&scal[threadIdx.x], r);
  }
}

__global__ void final_k(const float* __restrict__ scal, float* __restrict__ out) {
  if (threadIdx.x != 0 || blockIdx.x != 0) return;
  float S1 = scal[0], Sa1 = scal[1], S2 = scal[2], Sa2 = scal[3];
  float L1 = scal[4], La1 = scal[5], L2 = scal[6], La2 = scal[7];
  float NM = scal[8], Q2 = scal[9], Qa2 = scal[10];
  float intra = 0.5f * ((logf(S1) - L1 / NM) + (logf(Sa1) - La1 / NM));
  float inter = 0.5f * ((logf(S2) - L2 / NM) + (logf(Sa2) - La2 / NM));
  float unsup = 0.5f * (logf(S2) - Q2) + 0.5f * (logf(Sa2) - Qa2);
  out[0] = intra + 0.5f * inter + 0.5f * unsup;  // ALPHA=0.5, LAM=0.5
}

// ---------- host ----------
extern "C" void kernel_launch(void* const* d_in, const int* in_sizes, int n_in,
                              void* d_out, int out_size, void* d_ws, size_t ws_size,
                              hipStream_t stream) {
  const float* feats = (const float*)d_in[0];
  const int* ei = (const int*)d_in[1];
  const int* ea = (const int*)d_in[2];
  const int* pos = (const int*)d_in[3];
  const int* qp = (const int*)d_in[4];
  const float* Wq0 = (const float*)d_in[5];
  const float* bq0 = (const float*)d_in[6];
  const float* W0 = (const float*)d_in[7];
  const float* b0 = (const float*)d_in[8];
  const float* Whq0 = (const float*)d_in[9];
  const float* bhq0 = (const float*)d_in[10];
  const float* Wh0 = (const float*)d_in[11];
  const float* bh0 = (const float*)d_in[12];
  const float* Wf0 = (const float*)d_in[13];
  const float* bf0 = (const float*)d_in[14];
  const float* Wfh0 = (const float*)d_in[15];
  const float* bfh0 = (const float*)d_in[16];
  const float* aq0 = (const float*)d_in[17];
  const float* a0 = (const float*)d_in[18];
  const float* ahq0 = (const float*)d_in[19];
  const float* ah0 = (const float*)d_in[20];
  const float* aq_ = (const float*)d_in[21];
  const float* a_ = (const float*)d_in[22];
  const float* ahq_ = (const float*)d_in[23];
  const float* ah_ = (const float*)d_in[24];
  const float* Wlq = (const float*)d_in[25];
  const float* blq = (const float*)d_in[26];
  const float* Wlf = (const float*)d_in[27];
  const float* blf = (const float*)d_in[28];
  const float* Wm1 = (const float*)d_in[29];
  const float* bm1 = (const float*)d_in[30];
  const float* Wm2 = (const float*)d_in[31];
  const float* bm2 = (const float*)d_in[32];

  char* ws = (char*)d_ws;
  size_t off = 0;
  auto take = [&](size_t bytes) -> void* {
    void* p = ws + off;
    off = (off + bytes + 255) & ~(size_t)255;
    return p;
  };
  // ---- zero region ----
  int* cnt3 = (int*)take(3 * NN * 4);
  int* cursor3 = (int*)take(3 * NN * 4);
  int* aux = (int*)take(1024 * 4);
  int* maskI = (int*)take(NN * 4);
  float* s_hq = (float*)take(NN * 4);
  float* cntq = (float*)take(NN * 4);
  float* s_hgq = (float*)take(NN * 4);
  float* scal = (float*)take(64 * 4);
  size_t zero_end = off;
  // ---- non-zeroed scratch ----
  int* offs3 = (int*)take(3 * NN * 4);
  int* slots = (int*)take((size_t)3 * EE * 4);
  float* dinv = (float*)take(NN * 4);
  float* Binv = (float*)take(NN * 4);
  float* Dninv = (float*)take(NN * 4);
  float4* simbuf = (float4*)take((size_t)NN * 16);
  unsigned short* Wpack = (unsigned short*)take((size_t)7 * 16384 * 2);
  const size_t BFSZ = (size_t)NN * HH * 2;
  unsigned short* B0 = (unsigned short*)take(BFSZ);
  unsigned short* B1 = (unsigned short*)take(BFSZ);
  unsigned short* B2 = (unsigned short*)take(BFSZ);
  unsigned short* B3 = (unsigned short*)take(BFSZ);
  unsigned short* B4 = (unsigned short*)take(BFSZ);
  unsigned short* B5 = (unsigned short*)take(BFSZ);
  unsigned short* B6 = (unsigned short*)take(BFSZ);  // feats2 bf16
  unsigned char* P1 = (unsigned char*)take((size_t)NN * 256);  // fp8 pair [node][2][128]
  unsigned char* P2 = (unsigned char*)take((size_t)NN * 256);
  unsigned char* P3 = (unsigned char*)take((size_t)NN * 256);

  const int NB = (NN + 255) / 256;
  const int M3 = 3 * NN;
  const int SB = (M3 + 255) / 256;
  const int GMB = (NN + 63) / 64;    // gemm blocks (64 rows each)
  const int GTB = (NN + 7) / 8;      // gather blocks
  const int RB = (NN + 3) / 4;       // row-wave blocks
  const short8* Wp = (const short8*)Wpack;

  hipMemsetAsync(d_ws, 0, zero_end, stream);
  // CSR build (XCD-partitioned, high occupancy) + degrees + analytic query coefficients
  count_k<<<4096, 256, 0, stream>>>(ei, ea, qp, cnt3, cntq);
  derive_k<<<NB, 256, 0, stream>>>(cnt3, dinv, Binv, Dninv);
  scan1<<<SB, 256, 0, stream>>>(cnt3, offs3, aux, M3);
  scan2<<<1, 1024, 0, stream>>>(aux, SB);
  scan3<<<SB, 256, 0, stream>>>(offs3, aux, M3, pos, qp, maskI, s_hq, dinv);
  fill_k<<<4096, 256, 0, stream>>>(ei, ea, qp, offs3, cursor3, slots, dinv, Binv, cntq,
                                   s_hq, s_hgq);

  // dense prep
  pack_k<<<(7 * 2048 + 255) / 256, 256, 0, stream>>>(W0, Wh0, Wlf, Wf0, Wfh0, Wm1, Wm2,
                                                     Wpack);
  // feats @ {W0, Wh0, Wlf}: xw0 -> P1.half0 (fp8), xwh -> P2.half0 (fp8), feats2 -> B6 bf16
  gemm3_mfma<<<GMB, 256, 0, stream>>>(feats, Wp, blf, P1, P2, B6, NN);
  // hf_ = B3, hfh_ = B4
  fuse2_k<<<RB, 256, 0, stream>>>(B6, qp, Wlq, blq, aq_, a_, ahq_, ah_, B3, B4);
  // xwf -> P1.half1 ; xwfh -> P2.half1  (fp8, batched)
  gemm2_mfma<false, false, 2><<<2 * GMB, 256, 0, stream>>>(
      B3, B4, Wp + (size_t)3 * 2048, Wp + (size_t)4 * 2048, nullptr, nullptr, P1 + 128,
      P2 + 128, NN, GMB);
  // gathers: pass1 GCN P1 -> (B0=g0, B1=gf) bf16 ; pass2 HG-he P2 -> P3 fp8  [merged]
  dgather12_k<<<2 * GTB, 256, 0, stream>>>((const uint2*)P1, B0, B1, (const uint2*)P2,
                                           (uint2*)P3, offs3, cnt3, slots, dinv, Binv, GTB);
  // pass3 HG-node P3 -> (B2, B5) bf16
  dgather3_k<<<GTB, 256, 0, stream>>>((const uint2*)P3, B2, B5, offs3, cnt3, slots, Dninv);
  // hf = B3 ; h_augf = B4  (batched fuse+residual+relu; B3/B4 free after gemm2 above)
  fuse_add2_k<<<2 * RB, 256, 0, stream>>>(
      B0, B1, s_hq, nullptr, Wq0, bq0, b0, aq0, a0, bf0, B3,
      B2, B5, s_hgq, Dninv, Whq0, bhq0, bh0, ahq0, ah0, bfh0, B4, RB);
  // MLPs (batched per layer): L1: (B3->B0),(B4->B1) ; L2: (B0->B2=z),(B1->B5=z_aug) bf16
  gemm2_mfma<true, true, 1><<<2 * GMB, 256, 0, stream>>>(
      B3, B4, Wp + (size_t)5 * 2048, Wp + (size_t)5 * 2048, bm1, bm1, B0, B1, NN, GMB);
  gemm2_mfma<true, false, 1><<<2 * GMB, 256, 0, stream>>>(
      B0, B1, Wp + (size_t)6 * 2048, Wp + (size_t)6 * 2048, bm2, bm2, B2, B5, NN, GMB);
  // loss
  sim_k<<<RB, 256, 0, stream>>>(B2, B5, qp, simbuf, scal);
  reduce_sim_k<<<64, 256, 0, stream>>>(simbuf, maskI, scal);
  final_k<<<1, 64, 0, stream>>>(scal, (float*)d_out);
}